// Round 6
// baseline (507.277 us; speedup 1.0000x reference)
//
#include <hip/hip_runtime.h>
#include <cmath>

#define DM   1024
#define HDS  16
#define DH   64
#define DMLP 4096
#define TSEQ 2048
#define NROW 4096   // B*T = 2*2048

typedef short bf16x8 __attribute__((ext_vector_type(8)));
typedef float f32x4 __attribute__((ext_vector_type(4)));

__device__ __forceinline__ unsigned short f2bf(float f) {
  union { float f; unsigned u; } v; v.f = f;
  unsigned r = v.u + 0x7fffu + ((v.u >> 16) & 1u);
  return (unsigned short)(r >> 16);
}

__device__ __forceinline__ void gload_lds16(const void* g, void* l) {
  __builtin_amdgcn_global_load_lds(
      (const __attribute__((address_space(1))) unsigned int*)g,
      (__attribute__((address_space(3))) unsigned int*)l, 16, 0, 0);
}

// ---------- transpose fp32 [K][N] -> bf16 [N][K] ----------
__global__ __launch_bounds__(256) void tr_kernel(const float* __restrict__ in,
                                                 unsigned short* __restrict__ out,
                                                 int K, int N) {
  __shared__ unsigned short tile[32][33];
  int n0 = blockIdx.x * 32, k0 = blockIdx.y * 32;
  int tx = threadIdx.x & 31, ty = threadIdx.x >> 5;
#pragma unroll
  for (int j = 0; j < 4; ++j) {
    int k = ty + j * 8;
    tile[k][tx] = f2bf(in[(size_t)(k0 + k) * N + n0 + tx]);
  }
  __syncthreads();
#pragma unroll
  for (int j = 0; j < 4; ++j) {
    int n = ty + j * 8;
    out[(size_t)(n0 + n) * K + k0 + tx] = tile[tx][n];
  }
}

__global__ void concat3_kernel(const float* __restrict__ a, const float* __restrict__ b,
                               const float* __restrict__ c, float* __restrict__ out, int n) {
  int i = blockIdx.x * 256 + threadIdx.x;
  if (i < n) { out[i] = a[i]; out[n + i] = b[i]; out[2 * n + i] = c[i]; }
}

// ---------- rmsnorm fp32 [NROW][DM] -> bf16 ----------
__global__ __launch_bounds__(256) void rmsnorm_kernel(const float* __restrict__ x,
                                                      const float* __restrict__ w,
                                                      unsigned short* __restrict__ out) {
  int row = blockIdx.x;
  int t = threadIdx.x;
  const float4* xr = (const float4*)(x + (size_t)row * DM);
  float4 v = xr[t];
  float ss = v.x * v.x + v.y * v.y + v.z * v.z + v.w * v.w;
#pragma unroll
  for (int m = 1; m < 64; m <<= 1) ss += __shfl_xor(ss, m, 64);
  __shared__ float sred[4];
  if ((t & 63) == 0) sred[t >> 6] = ss;
  __syncthreads();
  ss = sred[0] + sred[1] + sred[2] + sred[3];
  float norm = rsqrtf(ss * (1.0f / DM) + 1e-6f);
  float4 wv = ((const float4*)w)[t];
  ushort4 o;
  o.x = f2bf(v.x * norm * wv.x);
  o.y = f2bf(v.y * norm * wv.y);
  o.z = f2bf(v.z * norm * wv.z);
  o.w = f2bf(v.w * norm * wv.w);
  ((ushort4*)out)[(size_t)row * (DM / 4) + t] = o;
}

// ---------- GEMM 128x128 tile (narrow-N path): C = A * BT^T + epilogue ----------
// EPI: 0 = +bias -> bf16 ; 1 = +bias + res -> f32 ; 2 = +bias, exact gelu -> bf16
// XCD-bijective blockIdx swizzle (T1): requires gridDim.x*gridDim.y % 8 == 0.
template <int EPI>
__global__ __launch_bounds__(256) void gemm_bt(const unsigned short* __restrict__ A,
                                               const unsigned short* __restrict__ BT,
                                               const float* __restrict__ bias,
                                               const float* __restrict__ res,
                                               void* __restrict__ outp,
                                               int M, int N, int K) {
  __shared__ alignas(16) unsigned short As[128 * 32];
  __shared__ alignas(16) unsigned short Bs[128 * 32];
  int tid = threadIdx.x;
  int w = tid >> 6, l = tid & 63;
  unsigned nx = gridDim.x;
  unsigned bidl = blockIdx.y * nx + blockIdx.x;
  unsigned nwg = nx * gridDim.y;
  unsigned cpx = nwg >> 3;
  unsigned sb = (bidl & 7) * cpx + (bidl >> 3);
  int m0 = (int)(sb / nx) * 128, n0 = (int)(sb % nx) * 128;
  int wr = w >> 1, wc = w & 1;
  f32x4 acc[4][4];
#pragma unroll
  for (int i = 0; i < 4; ++i)
#pragma unroll
    for (int j = 0; j < 4; ++j)
#pragma unroll
      for (int e = 0; e < 4; ++e) acc[i][j][e] = 0.0f;

  int nk = K >> 5;
  int arow = tid >> 2, aslot = tid & 3;  // 64 rows per half-tile, 4x16B slots per row
  for (int kt = 0; kt < nk; ++kt) {
    __syncthreads();
#pragma unroll
    for (int i = 0; i < 2; ++i) {
      int row = i * 64 + arow;
      gload_lds16(A + (size_t)(m0 + row) * K + (size_t)kt * 32 + aslot * 8,
                  (char*)As + i * 4096 + w * 1024);
      gload_lds16(BT + (size_t)(n0 + row) * K + (size_t)kt * 32 + aslot * 8,
                  (char*)Bs + i * 4096 + w * 1024);
    }
    __syncthreads();
    bf16x8 af[4], bfr[4];
#pragma unroll
    for (int mt = 0; mt < 4; ++mt)
      af[mt] = *(const bf16x8*)((const char*)As +
                (size_t)(wr * 64 + mt * 16 + (l & 15)) * 64 + (l >> 4) * 16);
#pragma unroll
    for (int nt = 0; nt < 4; ++nt)
      bfr[nt] = *(const bf16x8*)((const char*)Bs +
                 (size_t)(wc * 64 + nt * 16 + (l & 15)) * 64 + (l >> 4) * 16);
#pragma unroll
    for (int mt = 0; mt < 4; ++mt)
#pragma unroll
      for (int nt = 0; nt < 4; ++nt)
        acc[mt][nt] = __builtin_amdgcn_mfma_f32_16x16x32_bf16(af[mt], bfr[nt], acc[mt][nt], 0, 0, 0);
  }

  int g = l >> 4, c = l & 15;
#pragma unroll
  for (int mt = 0; mt < 4; ++mt) {
#pragma unroll
    for (int nt = 0; nt < 4; ++nt) {
#pragma unroll
      for (int r = 0; r < 4; ++r) {
        int m = m0 + wr * 64 + mt * 16 + g * 4 + r;
        int n = n0 + wc * 64 + nt * 16 + c;
        float v = acc[mt][nt][r] + bias[n];
        if (EPI == 2) v = 0.5f * v * (1.0f + erff(v * 0.70710678118654752f));
        if (EPI == 1) {
          v += res[(size_t)m * N + n];
          ((float*)outp)[(size_t)m * N + n] = v;
        } else {
          ((unsigned short*)outp)[(size_t)m * N + n] = f2bf(v);
        }
      }
    }
  }
}

// ---------- GEMM 256x256 tile, BK=64, 512 threads / 8 waves (2M x 4N) ----------
// Same 2-phase barrier structure as gemm_bt (parameter change inherits the
// verified template). Per wave: 128x64 output = acc[8][4] fragments.
template <int EPI>
__global__ __launch_bounds__(512) void gemm_bt256(const unsigned short* __restrict__ A,
                                                  const unsigned short* __restrict__ BT,
                                                  const float* __restrict__ bias,
                                                  const float* __restrict__ res,
                                                  void* __restrict__ outp,
                                                  int M, int N, int K) {
  __shared__ alignas(16) unsigned short As[256 * 64];  // 32 KB
  __shared__ alignas(16) unsigned short Bs[256 * 64];  // 32 KB
  int tid = threadIdx.x;
  int w = tid >> 6, l = tid & 63;
  int wr = w >> 2, wc = w & 3;
  unsigned nx = gridDim.x;
  unsigned bidl = blockIdx.y * nx + blockIdx.x;
  unsigned nwg = nx * gridDim.y;
  unsigned cpx = nwg >> 3;  // grid must be %8==0
  unsigned sb = (bidl & 7) * cpx + (bidl >> 3);
  int m0 = (int)(sb / nx) * 256, n0 = (int)(sb % nx) * 256;

  f32x4 acc[8][4];
#pragma unroll
  for (int i = 0; i < 8; ++i)
#pragma unroll
    for (int j = 0; j < 4; ++j)
#pragma unroll
      for (int e = 0; e < 4; ++e) acc[i][j][e] = 0.0f;

  int nk = K >> 6;
  int srow = tid >> 3, sslot = tid & 7;  // 64 rows x 8 slots per stage inst
  int c = l & 15, g = l >> 4;
  for (int kt = 0; kt < nk; ++kt) {
    __syncthreads();
#pragma unroll
    for (int i = 0; i < 4; ++i) {
      int row = i * 64 + srow;
      gload_lds16(A + (size_t)(m0 + row) * K + (size_t)kt * 64 + sslot * 8,
                  (char*)As + i * 8192 + w * 1024);
      gload_lds16(BT + (size_t)(n0 + row) * K + (size_t)kt * 64 + sslot * 8,
                  (char*)Bs + i * 8192 + w * 1024);
    }
    __syncthreads();
#pragma unroll
    for (int ks = 0; ks < 2; ++ks) {
      bf16x8 bfr[4];
#pragma unroll
      for (int nt = 0; nt < 4; ++nt)
        bfr[nt] = *(const bf16x8*)((const char*)Bs +
                   (size_t)(wc * 64 + nt * 16 + c) * 128 + ks * 64 + g * 16);
#pragma unroll
      for (int mt = 0; mt < 8; ++mt) {
        bf16x8 af = *(const bf16x8*)((const char*)As +
                     (size_t)(wr * 128 + mt * 16 + c) * 128 + ks * 64 + g * 16);
#pragma unroll
        for (int nt = 0; nt < 4; ++nt)
          acc[mt][nt] = __builtin_amdgcn_mfma_f32_16x16x32_bf16(af, bfr[nt], acc[mt][nt], 0, 0, 0);
      }
    }
  }

#pragma unroll
  for (int mt = 0; mt < 8; ++mt) {
#pragma unroll
    for (int nt = 0; nt < 4; ++nt) {
#pragma unroll
      for (int r = 0; r < 4; ++r) {
        int m = m0 + wr * 128 + mt * 16 + g * 4 + r;
        int n = n0 + wc * 64 + nt * 16 + c;
        float v = acc[mt][nt][r] + bias[n];
        if (EPI == 2) v = 0.5f * v * (1.0f + erff(v * 0.70710678118654752f));
        if (EPI == 1) {
          v += res[(size_t)m * N + n];
          ((float*)outp)[(size_t)m * N + n] = v;
        } else {
          ((unsigned short*)outp)[(size_t)m * N + n] = f2bf(v);
        }
      }
    }
  }
}

// ---------- V transpose: qkv v-part -> VT [bh][64 d][2048 t] bf16 ----------
__global__ __launch_bounds__(256) void vtr_kernel(const unsigned short* __restrict__ qkv,
                                                  unsigned short* __restrict__ vt) {
  __shared__ unsigned short tile[64][72];
  int bh = blockIdx.y, t0 = blockIdx.x * 64;
  int b = bh >> 4, h = bh & 15;
  int r = threadIdx.x >> 3, sl = threadIdx.x & 7;
#pragma unroll
  for (int half = 0; half < 2; ++half) {
    int rr = r + half * 32;
    bf16x8 v = *(const bf16x8*)(qkv + (size_t)(b * TSEQ + t0 + rr) * 3072 + 2048 + h * 64 + sl * 8);
    *(bf16x8*)&tile[rr][sl * 8] = v;  // row stride 144B (16B-aligned)
  }
  __syncthreads();
#pragma unroll
  for (int half = 0; half < 2; ++half) {
    int d = r + half * 32;
    bf16x8 o;
#pragma unroll
    for (int j = 0; j < 8; ++j) o[j] = (short)tile[sl * 8 + j][d];
    *(bf16x8*)(vt + ((size_t)bh * 64 + d) * TSEQ + t0 + sl * 8) = o;
  }
}

// ---------- causal flash attention v4 ----------
// 4 waves x 16 q-rows = 64 q/block; KVBLK=64; swizzled LDS; full online-softmax
// every tile; deferred final l-reduce; double-buffered reg staging.
__global__ __launch_bounds__(256) void attn_kernel(const unsigned short* __restrict__ qkv,
                                                   const unsigned short* __restrict__ vt,
                                                   unsigned short* __restrict__ attn_out) {
  __shared__ alignas(16) unsigned short Ks[2][64 * 64];  // [k][d] swz
  __shared__ alignas(16) unsigned short Vs[2][64 * 64];  // [d][k] swz
  __shared__ alignas(16) unsigned short Ps[4][16 * 64];  // per-wave [q][k] swz
  int tid = threadIdx.x, w = tid >> 6, l = tid & 63, g = l >> 4, c = l & 15;
  int bid = blockIdx.x;
  int qb = 31 - (bid & 31);             // heavy blocks dispatch first
  int bh = bid >> 5, b = bh >> 4, h = bh & 15;
  int q0 = qb * 64;
  int qw = q0 + w * 16;

  // Q fragments: rows qw + c, d-slices s*32 + g*8
  bf16x8 qf[2];
#pragma unroll
  for (int s = 0; s < 2; ++s)
    qf[s] = *(const bf16x8*)(qkv + (size_t)(b * TSEQ + qw + c) * 3072 + h * 64 + s * 32 + g * 8);

  f32x4 o[4];
  float mrow[4], lpart[4];
#pragma unroll
  for (int dc = 0; dc < 4; ++dc)
#pragma unroll
    for (int e = 0; e < 4; ++e) o[dc][e] = 0.0f;
#pragma unroll
  for (int r = 0; r < 4; ++r) { mrow[r] = -1e30f; lpart[r] = 0.0f; }

  int ntile = qb + 1;
  int sr = tid >> 3, ss = tid & 7;  // staging: 32 rows x 8 slots, 2 halves
  bf16x8 kreg[2], vreg[2];

#define LOADT(K0)                                                                       \
  {                                                                                     \
    _Pragma("unroll") for (int hf = 0; hf < 2; ++hf) {                                  \
      int rr = sr + hf * 32;                                                            \
      kreg[hf] = *(const bf16x8*)(qkv + (size_t)(b * TSEQ + (K0) + rr) * 3072 + 1024 +  \
                                  h * 64 + ss * 8);                                     \
      vreg[hf] = *(const bf16x8*)(vt + ((size_t)bh * 64 + rr) * TSEQ + (K0) + ss * 8);  \
    }                                                                                   \
  }
#define WRITET(BUF)                                                                     \
  {                                                                                     \
    _Pragma("unroll") for (int hf = 0; hf < 2; ++hf) {                                  \
      int rr = sr + hf * 32;                                                            \
      unsigned off = (unsigned)(rr * 128 + ss * 16) ^ (unsigned)((rr & 7) << 4);        \
      *(bf16x8*)((char*)Ks[BUF] + off) = kreg[hf];                                      \
      *(bf16x8*)((char*)Vs[BUF] + off) = vreg[hf];                                      \
    }                                                                                   \
  }

  LOADT(0);
  WRITET(0);
  __syncthreads();

  for (int t = 0; t < ntile; ++t) {
    int k0 = t << 6, cur = t & 1;
    if (t + 1 < ntile) LOADT((t + 1) << 6);

    {
      const char* Kb = (const char*)Ks[cur];
      const char* Vb = (const char*)Vs[cur];
      // S[4ni] = Q x K^T over d=64 (2 mfma steps each)
      f32x4 s[4];
#pragma unroll
      for (int ni = 0; ni < 4; ++ni) {
        int krow = ni * 16 + c;
        unsigned swz = (unsigned)((c & 7) << 4);
        bf16x8 kf0 = *(const bf16x8*)(Kb + (((unsigned)(krow * 128) + g * 16) ^ swz));
        bf16x8 kf1 = *(const bf16x8*)(Kb + (((unsigned)(krow * 128) + 64 + g * 16) ^ swz));
        f32x4 acc;
#pragma unroll
        for (int e = 0; e < 4; ++e) acc[e] = 0.0f;
        acc = __builtin_amdgcn_mfma_f32_16x16x32_bf16(qf[0], kf0, acc, 0, 0, 0);
        acc = __builtin_amdgcn_mfma_f32_16x16x32_bf16(qf[1], kf1, acc, 0, 0, 0);
        s[ni] = acc;
      }
      bool full = (k0 + 63 <= qw);  // no masking needed for any row of this wave
#pragma unroll
      for (int r = 0; r < 4; ++r) {
        int qg = qw + g * 4 + r;
        float pm[4];
#pragma unroll
        for (int ni = 0; ni < 4; ++ni) {
          float v = s[ni][r] * 0.125f;
          if (!full) {
            int kg = k0 + ni * 16 + c;
            v = (kg <= qg) ? v : -1e30f;
          }
          pm[ni] = v;
        }
        float mx = fmaxf(fmaxf(pm[0], pm[1]), fmaxf(pm[2], pm[3]));
        mx = fmaxf(mx, __shfl_xor(mx, 1, 64));
        mx = fmaxf(mx, __shfl_xor(mx, 2, 64));
        mx = fmaxf(mx, __shfl_xor(mx, 4, 64));
        mx = fmaxf(mx, __shfl_xor(mx, 8, 64));
        float mnew = fmaxf(mrow[r], mx);
        float scale = __expf(mrow[r] - mnew);
        mrow[r] = mnew;
        float p[4], rs = 0.0f;
#pragma unroll
        for (int ni = 0; ni < 4; ++ni) { p[ni] = __expf(pm[ni] - mnew); rs += p[ni]; }
        lpart[r] = lpart[r] * scale + rs;
#pragma unroll
        for (int dc = 0; dc < 4; ++dc) o[dc][r] *= scale;
        int prow = g * 4 + r;
        unsigned pswz = (unsigned)((prow & 7) << 4);
#pragma unroll
        for (int ni = 0; ni < 4; ++ni)
          *(unsigned short*)((char*)Ps[w] +
                             (((unsigned)(prow * 128 + (ni * 16 + c) * 2)) ^ pswz)) = f2bf(p[ni]);
      }
      asm volatile("s_waitcnt lgkmcnt(0)" ::: "memory");
      // PV: O[16q][64d] += P[16q][64k] x V[64k][64d]
      unsigned swz = (unsigned)((c & 7) << 4);
#pragma unroll
      for (int kc = 0; kc < 2; ++kc) {
        bf16x8 pf = *(const bf16x8*)((const char*)Ps[w] +
                     (((unsigned)(c * 128 + kc * 64 + g * 16)) ^ swz));
#pragma unroll
        for (int dc = 0; dc < 4; ++dc) {
          bf16x8 vf = *(const bf16x8*)(Vb +
                       (((unsigned)((dc * 16 + c) * 128 + kc * 64 + g * 16)) ^ swz));
          o[dc] = __builtin_amdgcn_mfma_f32_16x16x32_bf16(pf, vf, o[dc], 0, 0, 0);
        }
      }
    }

    if (t + 1 < ntile) {
      WRITET(cur ^ 1);
      __syncthreads();
    }
  }

#pragma unroll
  for (int r = 0; r < 4; ++r) {
    float lr = lpart[r];
    lr += __shfl_xor(lr, 1, 64);
    lr += __shfl_xor(lr, 2, 64);
    lr += __shfl_xor(lr, 4, 64);
    lr += __shfl_xor(lr, 8, 64);
    float inv = 1.0f / lr;
    size_t row = (size_t)b * TSEQ + qw + g * 4 + r;
    unsigned short* op = attn_out + row * 1024 + h * 64 + c;
#pragma unroll
    for (int dc = 0; dc < 4; ++dc) op[dc * 16] = f2bf(o[dc][r] * inv);
  }
#undef LOADT
#undef WRITET
}

extern "C" void kernel_launch(void* const* d_in, const int* in_sizes, int n_in,
                              void* d_out, int out_size, void* d_ws, size_t ws_size,
                              hipStream_t stream) {
  const float* x    = (const float*)d_in[0];
  const float* ln1w = (const float*)d_in[1];
  const float* ln2w = (const float*)d_in[2];
  const float* Wq   = (const float*)d_in[3];
  const float* bq   = (const float*)d_in[4];
  const float* Wk   = (const float*)d_in[5];
  const float* bk   = (const float*)d_in[6];
  const float* Wv   = (const float*)d_in[7];
  const float* bv   = (const float*)d_in[8];
  const float* Wo   = (const float*)d_in[9];
  const float* bo   = (const float*)d_in[10];
  const float* Wup  = (const float*)d_in[11];
  const float* bup  = (const float*)d_in[12];
  const float* Wdn  = (const float*)d_in[13];
  const float* bdn  = (const float*)d_in[14];

  char* ws = (char*)d_ws;
  unsigned short* xn1   = (unsigned short*)(ws + 0);              // 8 MB [4096][1024] bf16
  unsigned short* vtb   = (unsigned short*)(ws + 0);              // 8 MB [32][64][2048] bf16 (aliases xn1, dead by then)
  unsigned short* qkv   = (unsigned short*)(ws + (8ull << 20));   // 24 MB [4096][3072] bf16
  unsigned short* gbuf  = (unsigned short*)(ws + 0);              // 32 MB, aliases vtb+qkv (both dead)
  unsigned short* attn  = (unsigned short*)(ws + (32ull << 20));  // 8 MB [4096][1024] bf16
  float*          x2    = (float*)(ws + (40ull << 20));           // 16 MB [4096][1024] f32
  unsigned short* h2    = (unsigned short*)(ws + (56ull << 20));  // 8 MB
  unsigned short* WqkvT = (unsigned short*)(ws + (64ull << 20));  // 6 MB [3072][1024]
  unsigned short* WoT   = (unsigned short*)(ws + (70ull << 20));  // 2 MB [1024][1024]
  unsigned short* WupT  = (unsigned short*)(ws + (72ull << 20));  // 8 MB [4096][1024]
  unsigned short* WdnT  = (unsigned short*)(ws + (80ull << 20));  // 8 MB [1024][4096]
  float*          bqkv  = (float*)(ws + (88ull << 20));           // 12 KB [3072]

  dim3 blk(256);
  dim3 blk512(512);
  // weight transposes (fp32 -> bf16 W^T)
  tr_kernel<<<dim3(32, 32), blk, 0, stream>>>(Wq, WqkvT, 1024, 1024);
  tr_kernel<<<dim3(32, 32), blk, 0, stream>>>(Wk, WqkvT + 1024 * 1024, 1024, 1024);
  tr_kernel<<<dim3(32, 32), blk, 0, stream>>>(Wv, WqkvT + 2 * 1024 * 1024, 1024, 1024);
  tr_kernel<<<dim3(32, 32), blk, 0, stream>>>(Wo, WoT, 1024, 1024);
  tr_kernel<<<dim3(128, 32), blk, 0, stream>>>(Wup, WupT, 1024, 4096);
  tr_kernel<<<dim3(32, 128), blk, 0, stream>>>(Wdn, WdnT, 4096, 1024);
  concat3_kernel<<<dim3(4), blk, 0, stream>>>(bq, bk, bv, bqkv, 1024);

  // x -> rmsnorm -> qkv (256^2 tile: grid 12x16 = 192 blocks, %8==0)
  rmsnorm_kernel<<<dim3(NROW), blk, 0, stream>>>(x, ln1w, xn1);
  gemm_bt256<0><<<dim3(12, 16), blk512, 0, stream>>>(xn1, WqkvT, bqkv, nullptr, qkv, NROW, 3072, 1024);

  // V transpose then attention
  vtr_kernel<<<dim3(32, 32), blk, 0, stream>>>(qkv, vtb);
  attn_kernel<<<dim3(1024), blk, 0, stream>>>(qkv, vtb, attn);

  // x2 = x + attn @ Wo + bo (narrow N=1024: keep 128^2 path)
  gemm_bt<1><<<dim3(8, 32), blk, 0, stream>>>(attn, WoT, bo, x, x2, NROW, 1024, 1024);

  // mlp
  rmsnorm_kernel<<<dim3(NROW), blk, 0, stream>>>(x2, ln2w, h2);
  gemm_bt256<2><<<dim3(16, 16), blk512, 0, stream>>>(h2, WupT, bup, nullptr, gbuf, NROW, 4096, 1024);
  gemm_bt<1><<<dim3(8, 32), blk, 0, stream>>>(gbuf, WdnT, bdn, x2, d_out, NROW, 1024, 4096);
}

// Round 9
// 472.738 us; speedup vs baseline: 1.0731x; 1.0731x over previous
//
#include <hip/hip_runtime.h>
#include <cmath>

#define DM   1024
#define HDS  16
#define DH   64
#define DMLP 4096
#define TSEQ 2048
#define NROW 4096   // B*T = 2*2048

typedef short bf16x8 __attribute__((ext_vector_type(8)));
typedef float f32x4 __attribute__((ext_vector_type(4)));

__device__ __forceinline__ unsigned short f2bf(float f) {
  union { float f; unsigned u; } v; v.f = f;
  unsigned r = v.u + 0x7fffu + ((v.u >> 16) & 1u);
  return (unsigned short)(r >> 16);
}

__device__ __forceinline__ void gload_lds16(const void* g, void* l) {
  __builtin_amdgcn_global_load_lds(
      (const __attribute__((address_space(1))) unsigned int*)g,
      (__attribute__((address_space(3))) unsigned int*)l, 16, 0, 0);
}

// ---------- transpose fp32 [K][N] -> bf16 [N][K] ----------
__global__ __launch_bounds__(256) void tr_kernel(const float* __restrict__ in,
                                                 unsigned short* __restrict__ out,
                                                 int K, int N) {
  __shared__ unsigned short tile[32][33];
  int n0 = blockIdx.x * 32, k0 = blockIdx.y * 32;
  int tx = threadIdx.x & 31, ty = threadIdx.x >> 5;
#pragma unroll
  for (int j = 0; j < 4; ++j) {
    int k = ty + j * 8;
    tile[k][tx] = f2bf(in[(size_t)(k0 + k) * N + n0 + tx]);
  }
  __syncthreads();
#pragma unroll
  for (int j = 0; j < 4; ++j) {
    int n = ty + j * 8;
    out[(size_t)(n0 + n) * K + k0 + tx] = tile[tx][n];
  }
}

__global__ void concat3_kernel(const float* __restrict__ a, const float* __restrict__ b,
                               const float* __restrict__ c, float* __restrict__ out, int n) {
  int i = blockIdx.x * 256 + threadIdx.x;
  if (i < n) { out[i] = a[i]; out[n + i] = b[i]; out[2 * n + i] = c[i]; }
}

// ---------- rmsnorm fp32 [NROW][DM] -> bf16 ----------
__global__ __launch_bounds__(256) void rmsnorm_kernel(const float* __restrict__ x,
                                                      const float* __restrict__ w,
                                                      unsigned short* __restrict__ out) {
  int row = blockIdx.x;
  int t = threadIdx.x;
  const float4* xr = (const float4*)(x + (size_t)row * DM);
  float4 v = xr[t];
  float ss = v.x * v.x + v.y * v.y + v.z * v.z + v.w * v.w;
#pragma unroll
  for (int m = 1; m < 64; m <<= 1) ss += __shfl_xor(ss, m, 64);
  __shared__ float sred[4];
  if ((t & 63) == 0) sred[t >> 6] = ss;
  __syncthreads();
  ss = sred[0] + sred[1] + sred[2] + sred[3];
  float norm = rsqrtf(ss * (1.0f / DM) + 1e-6f);
  float4 wv = ((const float4*)w)[t];
  ushort4 o;
  o.x = f2bf(v.x * norm * wv.x);
  o.y = f2bf(v.y * norm * wv.y);
  o.z = f2bf(v.z * norm * wv.z);
  o.w = f2bf(v.w * norm * wv.w);
  ((ushort4*)out)[(size_t)row * (DM / 4) + t] = o;
}

// ---------- GEMM 128x128 tile, BK=32, double-buffered LDS prefetch ----------
// EPI: 0 = +bias -> bf16 ; 1 = +bias + res -> f32 ; 2 = +bias, exact gelu -> bf16
// XCD-bijective blockIdx swizzle (T1): requires gridDim.x*gridDim.y % 8 == 0.
template <int EPI>
__global__ __launch_bounds__(256) void gemm_bt(const unsigned short* __restrict__ A,
                                               const unsigned short* __restrict__ BT,
                                               const float* __restrict__ bias,
                                               const float* __restrict__ res,
                                               void* __restrict__ outp,
                                               int M, int N, int K) {
  __shared__ alignas(16) unsigned short As[2][128 * 32];
  __shared__ alignas(16) unsigned short Bs[2][128 * 32];
  int tid = threadIdx.x;
  int w = tid >> 6, l = tid & 63;
  unsigned nx = gridDim.x;
  unsigned bidl = blockIdx.y * nx + blockIdx.x;
  unsigned nwg = nx * gridDim.y;
  unsigned cpx = nwg >> 3;
  unsigned sb = (bidl & 7) * cpx + (bidl >> 3);
  int m0 = (int)(sb / nx) * 128, n0 = (int)(sb % nx) * 128;
  int wr = w >> 1, wc = w & 1;
  f32x4 acc[4][4];
#pragma unroll
  for (int i = 0; i < 4; ++i)
#pragma unroll
    for (int j = 0; j < 4; ++j)
#pragma unroll
      for (int e = 0; e < 4; ++e) acc[i][j][e] = 0.0f;

  int nk = K >> 5;
  int arow = tid >> 2, aslot = tid & 3;  // 64 rows per half-tile, 4x16B slots per row

#define STG128(BUF, KT)                                                            \
  {                                                                                \
    _Pragma("unroll") for (int i = 0; i < 2; ++i) {                                \
      int row = i * 64 + arow;                                                     \
      gload_lds16(A + (size_t)(m0 + row) * K + (size_t)(KT) * 32 + aslot * 8,      \
                  (char*)As[BUF] + i * 4096 + w * 1024);                           \
      gload_lds16(BT + (size_t)(n0 + row) * K + (size_t)(KT) * 32 + aslot * 8,     \
                  (char*)Bs[BUF] + i * 4096 + w * 1024);                           \
    }                                                                              \
  }

  STG128(0, 0);
  __syncthreads();
  int cur = 0;
  for (int kt = 0; kt < nk; ++kt) {
    if (kt + 1 < nk) STG128(cur ^ 1, kt + 1);
    bf16x8 af[4], bfr[4];
#pragma unroll
    for (int mt = 0; mt < 4; ++mt)
      af[mt] = *(const bf16x8*)((const char*)As[cur] +
                (size_t)(wr * 64 + mt * 16 + (l & 15)) * 64 + (l >> 4) * 16);
#pragma unroll
    for (int nt = 0; nt < 4; ++nt)
      bfr[nt] = *(const bf16x8*)((const char*)Bs[cur] +
                 (size_t)(wc * 64 + nt * 16 + (l & 15)) * 64 + (l >> 4) * 16);
#pragma unroll
    for (int mt = 0; mt < 4; ++mt)
#pragma unroll
      for (int nt = 0; nt < 4; ++nt)
        acc[mt][nt] = __builtin_amdgcn_mfma_f32_16x16x32_bf16(af[mt], bfr[nt], acc[mt][nt], 0, 0, 0);
    __syncthreads();  // drains vmcnt(0)+lgkmcnt(0) then barrier
    cur ^= 1;
  }
#undef STG128

  int g = l >> 4, c = l & 15;
#pragma unroll
  for (int mt = 0; mt < 4; ++mt) {
#pragma unroll
    for (int nt = 0; nt < 4; ++nt) {
#pragma unroll
      for (int r = 0; r < 4; ++r) {
        int m = m0 + wr * 64 + mt * 16 + g * 4 + r;
        int n = n0 + wc * 64 + nt * 16 + c;
        float v = acc[mt][nt][r] + bias[n];
        if (EPI == 2) v = 0.5f * v * (1.0f + erff(v * 0.70710678118654752f));
        if (EPI == 1) {
          v += res[(size_t)m * N + n];
          ((float*)outp)[(size_t)m * N + n] = v;
        } else {
          ((unsigned short*)outp)[(size_t)m * N + n] = f2bf(v);
        }
      }
    }
  }
}

// ---------- GEMM 256x256, BK=64, 8 waves, double-buffered + T2 swizzle ----------
// LDS dest linear (global_load_lds requirement); bank swizzle achieved by
// inverse-permuting the GLOBAL source 16B-slot (slot ^= row&7) and applying the
// same XOR on the ds_read side (rule #21: both-sides-or-neither involution).
template <int EPI>
__global__ __launch_bounds__(512) void gemm_db256(const unsigned short* __restrict__ A,
                                                  const unsigned short* __restrict__ BT,
                                                  const float* __restrict__ bias,
                                                  const float* __restrict__ res,
                                                  void* __restrict__ outp,
                                                  int M, int N, int K) {
  __shared__ alignas(16) unsigned short As[2][256 * 64];  // 2 x 32 KB
  __shared__ alignas(16) unsigned short Bs[2][256 * 64];  // 2 x 32 KB
  int tid = threadIdx.x;
  int w = tid >> 6, l = tid & 63;
  int wr = w >> 2, wc = w & 3;  // 2M x 4N waves
  unsigned nx = gridDim.x;
  unsigned bidl = blockIdx.y * nx + blockIdx.x;
  unsigned nwg = nx * gridDim.y;
  unsigned cpx = nwg >> 3;  // grid must be %8==0
  unsigned sb = (bidl & 7) * cpx + (bidl >> 3);
  int m0 = (int)(sb / nx) * 256, n0 = (int)(sb % nx) * 256;

  f32x4 acc[8][4];
#pragma unroll
  for (int i = 0; i < 8; ++i)
#pragma unroll
    for (int j = 0; j < 4; ++j)
#pragma unroll
      for (int e = 0; e < 4; ++e) acc[i][j][e] = 0.0f;

  int nk = K >> 6;
  int srow = tid >> 3, sslot = tid & 7;  // 64 rows x 8 slots per stage inst
  int gslot = sslot ^ (srow & 7);        // pre-swizzled source slot
  int c = l & 15, g = l >> 4;

#define STG256(BUF, KT)                                                            \
  {                                                                                \
    _Pragma("unroll") for (int i = 0; i < 4; ++i) {                                \
      int row = i * 64 + srow;                                                     \
      gload_lds16(A + (size_t)(m0 + row) * K + (size_t)(KT) * 64 + gslot * 8,      \
                  (char*)As[BUF] + i * 8192 + w * 1024);                           \
      gload_lds16(BT + (size_t)(n0 + row) * K + (size_t)(KT) * 64 + gslot * 8,     \
                  (char*)Bs[BUF] + i * 8192 + w * 1024);                           \
    }                                                                              \
  }

  STG256(0, 0);
  __syncthreads();
  int cur = 0;
  for (int kt = 0; kt < nk; ++kt) {
    if (kt + 1 < nk) STG256(cur ^ 1, kt + 1);
#pragma unroll
    for (int ks = 0; ks < 2; ++ks) {
      bf16x8 bfr[4];
#pragma unroll
      for (int nt = 0; nt < 4; ++nt) {
        int brow = wc * 64 + nt * 16 + c;
        unsigned bslot = (unsigned)((ks * 4 + g) ^ (brow & 7));
        bfr[nt] = *(const bf16x8*)((const char*)Bs[cur] + (size_t)brow * 128 + bslot * 16);
      }
#pragma unroll
      for (int mt = 0; mt < 8; ++mt) {
        int arow2 = wr * 128 + mt * 16 + c;
        unsigned aslot2 = (unsigned)((ks * 4 + g) ^ (arow2 & 7));
        bf16x8 af = *(const bf16x8*)((const char*)As[cur] + (size_t)arow2 * 128 + aslot2 * 16);
#pragma unroll
        for (int nt = 0; nt < 4; ++nt)
          acc[mt][nt] = __builtin_amdgcn_mfma_f32_16x16x32_bf16(af, bfr[nt], acc[mt][nt], 0, 0, 0);
      }
    }
    __syncthreads();  // drains vmcnt(0)+lgkmcnt(0) then barrier
    cur ^= 1;
  }
#undef STG256

#pragma unroll
  for (int mt = 0; mt < 8; ++mt) {
#pragma unroll
    for (int nt = 0; nt < 4; ++nt) {
#pragma unroll
      for (int r = 0; r < 4; ++r) {
        int m = m0 + wr * 128 + mt * 16 + g * 4 + r;
        int n = n0 + wc * 64 + nt * 16 + c;
        float v = acc[mt][nt][r] + bias[n];
        if (EPI == 2) v = 0.5f * v * (1.0f + erff(v * 0.70710678118654752f));
        if (EPI == 1) {
          v += res[(size_t)m * N + n];
          ((float*)outp)[(size_t)m * N + n] = v;
        } else {
          ((unsigned short*)outp)[(size_t)m * N + n] = f2bf(v);
        }
      }
    }
  }
}

// ---------- V transpose: qkv v-part -> VT [bh][64 d][2048 t] bf16 ----------
__global__ __launch_bounds__(256) void vtr_kernel(const unsigned short* __restrict__ qkv,
                                                  unsigned short* __restrict__ vt) {
  __shared__ unsigned short tile[64][72];
  int bh = blockIdx.y, t0 = blockIdx.x * 64;
  int b = bh >> 4, h = bh & 15;
  int r = threadIdx.x >> 3, sl = threadIdx.x & 7;
#pragma unroll
  for (int half = 0; half < 2; ++half) {
    int rr = r + half * 32;
    bf16x8 v = *(const bf16x8*)(qkv + (size_t)(b * TSEQ + t0 + rr) * 3072 + 2048 + h * 64 + sl * 8);
    *(bf16x8*)&tile[rr][sl * 8] = v;  // row stride 144B (16B-aligned)
  }
  __syncthreads();
#pragma unroll
  for (int half = 0; half < 2; ++half) {
    int d = r + half * 32;
    bf16x8 o;
#pragma unroll
    for (int j = 0; j < 8; ++j) o[j] = (short)tile[sl * 8 + j][d];
    *(bf16x8*)(vt + ((size_t)bh * 64 + d) * TSEQ + t0 + sl * 8) = o;
  }
}

// ---------- causal flash attention v4 ----------
// 4 waves x 16 q-rows = 64 q/block; KVBLK=64; swizzled LDS; full online-softmax
// every tile; deferred final l-reduce; double-buffered reg staging.
__global__ __launch_bounds__(256) void attn_kernel(const unsigned short* __restrict__ qkv,
                                                   const unsigned short* __restrict__ vt,
                                                   unsigned short* __restrict__ attn_out) {
  __shared__ alignas(16) unsigned short Ks[2][64 * 64];  // [k][d] swz
  __shared__ alignas(16) unsigned short Vs[2][64 * 64];  // [d][k] swz
  __shared__ alignas(16) unsigned short Ps[4][16 * 64];  // per-wave [q][k] swz
  int tid = threadIdx.x, w = tid >> 6, l = tid & 63, g = l >> 4, c = l & 15;
  int bid = blockIdx.x;
  int qb = 31 - (bid & 31);             // heavy blocks dispatch first
  int bh = bid >> 5, b = bh >> 4, h = bh & 15;
  int q0 = qb * 64;
  int qw = q0 + w * 16;

  // Q fragments: rows qw + c, d-slices s*32 + g*8
  bf16x8 qf[2];
#pragma unroll
  for (int s = 0; s < 2; ++s)
    qf[s] = *(const bf16x8*)(qkv + (size_t)(b * TSEQ + qw + c) * 3072 + h * 64 + s * 32 + g * 8);

  f32x4 o[4];
  float mrow[4], lpart[4];
#pragma unroll
  for (int dc = 0; dc < 4; ++dc)
#pragma unroll
    for (int e = 0; e < 4; ++e) o[dc][e] = 0.0f;
#pragma unroll
  for (int r = 0; r < 4; ++r) { mrow[r] = -1e30f; lpart[r] = 0.0f; }

  int ntile = qb + 1;
  int sr = tid >> 3, ss = tid & 7;  // staging: 32 rows x 8 slots, 2 halves
  bf16x8 kreg[2], vreg[2];

#define LOADT(K0)                                                                       \
  {                                                                                     \
    _Pragma("unroll") for (int hf = 0; hf < 2; ++hf) {                                  \
      int rr = sr + hf * 32;                                                            \
      kreg[hf] = *(const bf16x8*)(qkv + (size_t)(b * TSEQ + (K0) + rr) * 3072 + 1024 +  \
                                  h * 64 + ss * 8);                                     \
      vreg[hf] = *(const bf16x8*)(vt + ((size_t)bh * 64 + rr) * TSEQ + (K0) + ss * 8);  \
    }                                                                                   \
  }
#define WRITET(BUF)                                                                     \
  {                                                                                     \
    _Pragma("unroll") for (int hf = 0; hf < 2; ++hf) {                                  \
      int rr = sr + hf * 32;                                                            \
      unsigned off = (unsigned)(rr * 128 + ss * 16) ^ (unsigned)((rr & 7) << 4);        \
      *(bf16x8*)((char*)Ks[BUF] + off) = kreg[hf];                                      \
      *(bf16x8*)((char*)Vs[BUF] + off) = vreg[hf];                                      \
    }                                                                                   \
  }

  LOADT(0);
  WRITET(0);
  __syncthreads();

  for (int t = 0; t < ntile; ++t) {
    int k0 = t << 6, cur = t & 1;
    if (t + 1 < ntile) LOADT((t + 1) << 6);

    {
      const char* Kb = (const char*)Ks[cur];
      const char* Vb = (const char*)Vs[cur];
      // S[4ni] = Q x K^T over d=64 (2 mfma steps each)
      f32x4 s[4];
#pragma unroll
      for (int ni = 0; ni < 4; ++ni) {
        int krow = ni * 16 + c;
        unsigned swz = (unsigned)((c & 7) << 4);
        bf16x8 kf0 = *(const bf16x8*)(Kb + (((unsigned)(krow * 128) + g * 16) ^ swz));
        bf16x8 kf1 = *(const bf16x8*)(Kb + (((unsigned)(krow * 128) + 64 + g * 16) ^ swz));
        f32x4 acc;
#pragma unroll
        for (int e = 0; e < 4; ++e) acc[e] = 0.0f;
        acc = __builtin_amdgcn_mfma_f32_16x16x32_bf16(qf[0], kf0, acc, 0, 0, 0);
        acc = __builtin_amdgcn_mfma_f32_16x16x32_bf16(qf[1], kf1, acc, 0, 0, 0);
        s[ni] = acc;
      }
      bool full = (k0 + 63 <= qw);  // no masking needed for any row of this wave
#pragma unroll
      for (int r = 0; r < 4; ++r) {
        int qg = qw + g * 4 + r;
        float pm[4];
#pragma unroll
        for (int ni = 0; ni < 4; ++ni) {
          float v = s[ni][r] * 0.125f;
          if (!full) {
            int kg = k0 + ni * 16 + c;
            v = (kg <= qg) ? v : -1e30f;
          }
          pm[ni] = v;
        }
        float mx = fmaxf(fmaxf(pm[0], pm[1]), fmaxf(pm[2], pm[3]));
        mx = fmaxf(mx, __shfl_xor(mx, 1, 64));
        mx = fmaxf(mx, __shfl_xor(mx, 2, 64));
        mx = fmaxf(mx, __shfl_xor(mx, 4, 64));
        mx = fmaxf(mx, __shfl_xor(mx, 8, 64));
        float mnew = fmaxf(mrow[r], mx);
        float scale = __expf(mrow[r] - mnew);
        mrow[r] = mnew;
        float p[4], rs = 0.0f;
#pragma unroll
        for (int ni = 0; ni < 4; ++ni) { p[ni] = __expf(pm[ni] - mnew); rs += p[ni]; }
        lpart[r] = lpart[r] * scale + rs;
#pragma unroll
        for (int dc = 0; dc < 4; ++dc) o[dc][r] *= scale;
        int prow = g * 4 + r;
        unsigned pswz = (unsigned)((prow & 7) << 4);
#pragma unroll
        for (int ni = 0; ni < 4; ++ni)
          *(unsigned short*)((char*)Ps[w] +
                             (((unsigned)(prow * 128 + (ni * 16 + c) * 2)) ^ pswz)) = f2bf(p[ni]);
      }
      asm volatile("s_waitcnt lgkmcnt(0)" ::: "memory");
      // PV: O[16q][64d] += P[16q][64k] x V[64k][64d]
      unsigned swz = (unsigned)((c & 7) << 4);
#pragma unroll
      for (int kc = 0; kc < 2; ++kc) {
        bf16x8 pf = *(const bf16x8*)((const char*)Ps[w] +
                     (((unsigned)(c * 128 + kc * 64 + g * 16)) ^ swz));
#pragma unroll
        for (int dc = 0; dc < 4; ++dc) {
          bf16x8 vf = *(const bf16x8*)(Vb +
                       (((unsigned)((dc * 16 + c) * 128 + kc * 64 + g * 16)) ^ swz));
          o[dc] = __builtin_amdgcn_mfma_f32_16x16x32_bf16(pf, vf, o[dc], 0, 0, 0);
        }
      }
    }

    if (t + 1 < ntile) {
      WRITET(cur ^ 1);
      __syncthreads();
    }
  }

#pragma unroll
  for (int r = 0; r < 4; ++r) {
    float lr = lpart[r];
    lr += __shfl_xor(lr, 1, 64);
    lr += __shfl_xor(lr, 2, 64);
    lr += __shfl_xor(lr, 4, 64);
    lr += __shfl_xor(lr, 8, 64);
    float inv = 1.0f / lr;
    size_t row = (size_t)b * TSEQ + qw + g * 4 + r;
    unsigned short* op = attn_out + row * 1024 + h * 64 + c;
#pragma unroll
    for (int dc = 0; dc < 4; ++dc) op[dc * 16] = f2bf(o[dc][r] * inv);
  }
#undef LOADT
#undef WRITET
}

extern "C" void kernel_launch(void* const* d_in, const int* in_sizes, int n_in,
                              void* d_out, int out_size, void* d_ws, size_t ws_size,
                              hipStream_t stream) {
  const float* x    = (const float*)d_in[0];
  const float* ln1w = (const float*)d_in[1];
  const float* ln2w = (const float*)d_in[2];
  const float* Wq   = (const float*)d_in[3];
  const float* bq   = (const float*)d_in[4];
  const float* Wk   = (const float*)d_in[5];
  const float* bk   = (const float*)d_in[6];
  const float* Wv   = (const float*)d_in[7];
  const float* bv   = (const float*)d_in[8];
  const float* Wo   = (const float*)d_in[9];
  const float* bo   = (const float*)d_in[10];
  const float* Wup  = (const float*)d_in[11];
  const float* bup  = (const float*)d_in[12];
  const float* Wdn  = (const float*)d_in[13];
  const float* bdn  = (const float*)d_in[14];

  char* ws = (char*)d_ws;
  unsigned short* xn1   = (unsigned short*)(ws + 0);              // 8 MB [4096][1024] bf16
  unsigned short* vtb   = (unsigned short*)(ws + 0);              // 8 MB [32][64][2048] bf16 (aliases xn1, dead by then)
  unsigned short* qkv   = (unsigned short*)(ws + (8ull << 20));   // 24 MB [4096][3072] bf16
  unsigned short* gbuf  = (unsigned short*)(ws + 0);              // 32 MB, aliases vtb+qkv (both dead)
  unsigned short* attn  = (unsigned short*)(ws + (32ull << 20));  // 8 MB [4096][1024] bf16
  float*          x2    = (float*)(ws + (40ull << 20));           // 16 MB [4096][1024] f32
  unsigned short* h2    = (unsigned short*)(ws + (56ull << 20));  // 8 MB
  unsigned short* WqkvT = (unsigned short*)(ws + (64ull << 20));  // 6 MB [3072][1024]
  unsigned short* WoT   = (unsigned short*)(ws + (70ull << 20));  // 2 MB [1024][1024]
  unsigned short* WupT  = (unsigned short*)(ws + (72ull << 20));  // 8 MB [4096][1024]
  unsigned short* WdnT  = (unsigned short*)(ws + (80ull << 20));  // 8 MB [1024][4096]
  float*          bqkv  = (float*)(ws + (88ull << 20));           // 12 KB [3072]

  dim3 blk(256);
  dim3 blk512(512);
  // weight transposes (fp32 -> bf16 W^T)
  tr_kernel<<<dim3(32, 32), blk, 0, stream>>>(Wq, WqkvT, 1024, 1024);
  tr_kernel<<<dim3(32, 32), blk, 0, stream>>>(Wk, WqkvT + 1024 * 1024, 1024, 1024);
  tr_kernel<<<dim3(32, 32), blk, 0, stream>>>(Wv, WqkvT + 2 * 1024 * 1024, 1024, 1024);
  tr_kernel<<<dim3(32, 32), blk, 0, stream>>>(Wo, WoT, 1024, 1024);
  tr_kernel<<<dim3(128, 32), blk, 0, stream>>>(Wup, WupT, 1024, 4096);
  tr_kernel<<<dim3(32, 128), blk, 0, stream>>>(Wdn, WdnT, 4096, 1024);
  concat3_kernel<<<dim3(4), blk, 0, stream>>>(bq, bk, bv, bqkv, 1024);

  // x -> rmsnorm -> qkv (256^2 dbuf tile: grid 12x16 = 192 blocks, %8==0)
  rmsnorm_kernel<<<dim3(NROW), blk, 0, stream>>>(x, ln1w, xn1);
  gemm_db256<0><<<dim3(12, 16), blk512, 0, stream>>>(xn1, WqkvT, bqkv, nullptr, qkv, NROW, 3072, 1024);

  // V transpose then attention
  vtr_kernel<<<dim3(32, 32), blk, 0, stream>>>(qkv, vtb);
  attn_kernel<<<dim3(1024), blk, 0, stream>>>(qkv, vtb, attn);

  // x2 = x + attn @ Wo + bo (narrow N=1024: 128^2 dbuf path)
  gemm_bt<1><<<dim3(8, 32), blk, 0, stream>>>(attn, WoT, bo, x, x2, NROW, 1024, 1024);

  // mlp
  rmsnorm_kernel<<<dim3(NROW), blk, 0, stream>>>(x2, ln2w, h2);
  gemm_db256<2><<<dim3(16, 16), blk512, 0, stream>>>(h2, WupT, bup, nullptr, gbuf, NROW, 4096, 1024);
  gemm_bt<1><<<dim3(8, 32), blk, 0, stream>>>(gbuf, WdnT, bdn, x2, d_out, NROW, 1024, 4096);
}

// Round 10
// 418.163 us; speedup vs baseline: 1.2131x; 1.1305x over previous
//
#include <hip/hip_runtime.h>
#include <cmath>

#define DM   1024
#define HDS  16
#define DH   64
#define DMLP 4096
#define TSEQ 2048
#define NROW 4096   // B*T = 2*2048

typedef short bf16x8 __attribute__((ext_vector_type(8)));
typedef float f32x4 __attribute__((ext_vector_type(4)));

__device__ __forceinline__ unsigned short f2bf(float f) {
  union { float f; unsigned u; } v; v.f = f;
  unsigned r = v.u + 0x7fffu + ((v.u >> 16) & 1u);
  return (unsigned short)(r >> 16);
}

__device__ __forceinline__ void gload_lds16(const void* g, void* l) {
  __builtin_amdgcn_global_load_lds(
      (const __attribute__((address_space(1))) unsigned int*)g,
      (__attribute__((address_space(3))) unsigned int*)l, 16, 0, 0);
}

// ---------- transpose fp32 [K][N] -> bf16 [N][K] ----------
__global__ __launch_bounds__(256) void tr_kernel(const float* __restrict__ in,
                                                 unsigned short* __restrict__ out,
                                                 int K, int N) {
  __shared__ unsigned short tile[32][33];
  int n0 = blockIdx.x * 32, k0 = blockIdx.y * 32;
  int tx = threadIdx.x & 31, ty = threadIdx.x >> 5;
#pragma unroll
  for (int j = 0; j < 4; ++j) {
    int k = ty + j * 8;
    tile[k][tx] = f2bf(in[(size_t)(k0 + k) * N + n0 + tx]);
  }
  __syncthreads();
#pragma unroll
  for (int j = 0; j < 4; ++j) {
    int n = ty + j * 8;
    out[(size_t)(n0 + n) * K + k0 + tx] = tile[tx][n];
  }
}

__global__ void concat3_kernel(const float* __restrict__ a, const float* __restrict__ b,
                               const float* __restrict__ c, float* __restrict__ out, int n) {
  int i = blockIdx.x * 256 + threadIdx.x;
  if (i < n) { out[i] = a[i]; out[n + i] = b[i]; out[2 * n + i] = c[i]; }
}

// ---------- rmsnorm fp32 [NROW][DM] -> bf16 ----------
__global__ __launch_bounds__(256) void rmsnorm_kernel(const float* __restrict__ x,
                                                      const float* __restrict__ w,
                                                      unsigned short* __restrict__ out) {
  int row = blockIdx.x;
  int t = threadIdx.x;
  const float4* xr = (const float4*)(x + (size_t)row * DM);
  float4 v = xr[t];
  float ss = v.x * v.x + v.y * v.y + v.z * v.z + v.w * v.w;
#pragma unroll
  for (int m = 1; m < 64; m <<= 1) ss += __shfl_xor(ss, m, 64);
  __shared__ float sred[4];
  if ((t & 63) == 0) sred[t >> 6] = ss;
  __syncthreads();
  ss = sred[0] + sred[1] + sred[2] + sred[3];
  float norm = rsqrtf(ss * (1.0f / DM) + 1e-6f);
  float4 wv = ((const float4*)w)[t];
  ushort4 o;
  o.x = f2bf(v.x * norm * wv.x);
  o.y = f2bf(v.y * norm * wv.y);
  o.z = f2bf(v.z * norm * wv.z);
  o.w = f2bf(v.w * norm * wv.w);
  ((ushort4*)out)[(size_t)row * (DM / 4) + t] = o;
}

// ---------- GEMM 128x128 tile, BK=32, double-buffered LDS prefetch ----------
// EPI: 0 = +bias -> bf16 ; 1 = +bias + res -> f32 ; 2 = +bias, exact gelu -> bf16
// XCD-bijective blockIdx swizzle (T1): requires gridDim.x*gridDim.y % 8 == 0.
template <int EPI>
__global__ __launch_bounds__(256) void gemm_bt(const unsigned short* __restrict__ A,
                                               const unsigned short* __restrict__ BT,
                                               const float* __restrict__ bias,
                                               const float* __restrict__ res,
                                               void* __restrict__ outp,
                                               int M, int N, int K) {
  __shared__ alignas(16) unsigned short As[2][128 * 32];
  __shared__ alignas(16) unsigned short Bs[2][128 * 32];
  int tid = threadIdx.x;
  int w = tid >> 6, l = tid & 63;
  unsigned nx = gridDim.x;
  unsigned bidl = blockIdx.y * nx + blockIdx.x;
  unsigned nwg = nx * gridDim.y;
  unsigned cpx = nwg >> 3;
  unsigned sb = (bidl & 7) * cpx + (bidl >> 3);
  int m0 = (int)(sb / nx) * 128, n0 = (int)(sb % nx) * 128;
  int wr = w >> 1, wc = w & 1;
  f32x4 acc[4][4];
#pragma unroll
  for (int i = 0; i < 4; ++i)
#pragma unroll
    for (int j = 0; j < 4; ++j)
#pragma unroll
      for (int e = 0; e < 4; ++e) acc[i][j][e] = 0.0f;

  int nk = K >> 5;
  int arow = tid >> 2, aslot = tid & 3;  // 64 rows per half-tile, 4x16B slots per row

#define STG128(BUF, KT)                                                            \
  {                                                                                \
    _Pragma("unroll") for (int i = 0; i < 2; ++i) {                                \
      int row = i * 64 + arow;                                                     \
      gload_lds16(A + (size_t)(m0 + row) * K + (size_t)(KT) * 32 + aslot * 8,      \
                  (char*)As[BUF] + i * 4096 + w * 1024);                           \
      gload_lds16(BT + (size_t)(n0 + row) * K + (size_t)(KT) * 32 + aslot * 8,     \
                  (char*)Bs[BUF] + i * 4096 + w * 1024);                           \
    }                                                                              \
  }

  STG128(0, 0);
  __syncthreads();
  int cur = 0;
  for (int kt = 0; kt < nk; ++kt) {
    if (kt + 1 < nk) STG128(cur ^ 1, kt + 1);
    bf16x8 af[4], bfr[4];
#pragma unroll
    for (int mt = 0; mt < 4; ++mt)
      af[mt] = *(const bf16x8*)((const char*)As[cur] +
                (size_t)(wr * 64 + mt * 16 + (l & 15)) * 64 + (l >> 4) * 16);
#pragma unroll
    for (int nt = 0; nt < 4; ++nt)
      bfr[nt] = *(const bf16x8*)((const char*)Bs[cur] +
                 (size_t)(wc * 64 + nt * 16 + (l & 15)) * 64 + (l >> 4) * 16);
#pragma unroll
    for (int mt = 0; mt < 4; ++mt)
#pragma unroll
      for (int nt = 0; nt < 4; ++nt)
        acc[mt][nt] = __builtin_amdgcn_mfma_f32_16x16x32_bf16(af[mt], bfr[nt], acc[mt][nt], 0, 0, 0);
    __syncthreads();  // drains vmcnt(0)+lgkmcnt(0) then barrier
    cur ^= 1;
  }
#undef STG128

  int g = l >> 4, c = l & 15;
#pragma unroll
  for (int mt = 0; mt < 4; ++mt) {
#pragma unroll
    for (int nt = 0; nt < 4; ++nt) {
#pragma unroll
      for (int r = 0; r < 4; ++r) {
        int m = m0 + wr * 64 + mt * 16 + g * 4 + r;
        int n = n0 + wc * 64 + nt * 16 + c;
        float v = acc[mt][nt][r] + bias[n];
        if (EPI == 2) v = 0.5f * v * (1.0f + erff(v * 0.70710678118654752f));
        if (EPI == 1) {
          v += res[(size_t)m * N + n];
          ((float*)outp)[(size_t)m * N + n] = v;
        } else {
          ((unsigned short*)outp)[(size_t)m * N + n] = f2bf(v);
        }
      }
    }
  }
}

// ---------- GEMM 256x256, BK=64, 8 waves, double-buffered + T2 swizzle ----------
// LDS dest linear (global_load_lds requirement); bank swizzle achieved by
// inverse-permuting the GLOBAL source 16B-slot (slot ^= row&7) and applying the
// same XOR on the ds_read side (rule #21: both-sides-or-neither involution).
template <int EPI>
__global__ __launch_bounds__(512) void gemm_db256(const unsigned short* __restrict__ A,
                                                  const unsigned short* __restrict__ BT,
                                                  const float* __restrict__ bias,
                                                  const float* __restrict__ res,
                                                  void* __restrict__ outp,
                                                  int M, int N, int K) {
  __shared__ alignas(16) unsigned short As[2][256 * 64];  // 2 x 32 KB
  __shared__ alignas(16) unsigned short Bs[2][256 * 64];  // 2 x 32 KB
  int tid = threadIdx.x;
  int w = tid >> 6, l = tid & 63;
  int wr = w >> 2, wc = w & 3;  // 2M x 4N waves
  unsigned nx = gridDim.x;
  unsigned bidl = blockIdx.y * nx + blockIdx.x;
  unsigned nwg = nx * gridDim.y;
  unsigned cpx = nwg >> 3;  // grid must be %8==0
  unsigned sb = (bidl & 7) * cpx + (bidl >> 3);
  int m0 = (int)(sb / nx) * 256, n0 = (int)(sb % nx) * 256;

  f32x4 acc[8][4];
#pragma unroll
  for (int i = 0; i < 8; ++i)
#pragma unroll
    for (int j = 0; j < 4; ++j)
#pragma unroll
      for (int e = 0; e < 4; ++e) acc[i][j][e] = 0.0f;

  int nk = K >> 6;
  int srow = tid >> 3, sslot = tid & 7;  // 64 rows x 8 slots per stage inst
  int gslot = sslot ^ (srow & 7);        // pre-swizzled source slot
  int c = l & 15, g = l >> 4;

#define STG256(BUF, KT)                                                            \
  {                                                                                \
    _Pragma("unroll") for (int i = 0; i < 4; ++i) {                                \
      int row = i * 64 + srow;                                                     \
      gload_lds16(A + (size_t)(m0 + row) * K + (size_t)(KT) * 64 + gslot * 8,      \
                  (char*)As[BUF] + i * 8192 + w * 1024);                           \
      gload_lds16(BT + (size_t)(n0 + row) * K + (size_t)(KT) * 64 + gslot * 8,     \
                  (char*)Bs[BUF] + i * 8192 + w * 1024);                           \
    }                                                                              \
  }

  STG256(0, 0);
  __syncthreads();
  int cur = 0;
  for (int kt = 0; kt < nk; ++kt) {
    if (kt + 1 < nk) STG256(cur ^ 1, kt + 1);
#pragma unroll
    for (int ks = 0; ks < 2; ++ks) {
      bf16x8 bfr[4];
#pragma unroll
      for (int nt = 0; nt < 4; ++nt) {
        int brow = wc * 64 + nt * 16 + c;
        unsigned bslot = (unsigned)((ks * 4 + g) ^ (brow & 7));
        bfr[nt] = *(const bf16x8*)((const char*)Bs[cur] + (size_t)brow * 128 + bslot * 16);
      }
#pragma unroll
      for (int mt = 0; mt < 8; ++mt) {
        int arow2 = wr * 128 + mt * 16 + c;
        unsigned aslot2 = (unsigned)((ks * 4 + g) ^ (arow2 & 7));
        bf16x8 af = *(const bf16x8*)((const char*)As[cur] + (size_t)arow2 * 128 + aslot2 * 16);
#pragma unroll
        for (int nt = 0; nt < 4; ++nt)
          acc[mt][nt] = __builtin_amdgcn_mfma_f32_16x16x32_bf16(af, bfr[nt], acc[mt][nt], 0, 0, 0);
      }
    }
    __syncthreads();  // drains vmcnt(0)+lgkmcnt(0) then barrier
    cur ^= 1;
  }
#undef STG256

#pragma unroll
  for (int mt = 0; mt < 8; ++mt) {
#pragma unroll
    for (int nt = 0; nt < 4; ++nt) {
#pragma unroll
      for (int r = 0; r < 4; ++r) {
        int m = m0 + wr * 128 + mt * 16 + g * 4 + r;
        int n = n0 + wc * 64 + nt * 16 + c;
        float v = acc[mt][nt][r] + bias[n];
        if (EPI == 2) v = 0.5f * v * (1.0f + erff(v * 0.70710678118654752f));
        if (EPI == 1) {
          v += res[(size_t)m * N + n];
          ((float*)outp)[(size_t)m * N + n] = v;
        } else {
          ((unsigned short*)outp)[(size_t)m * N + n] = f2bf(v);
        }
      }
    }
  }
}

// ---------- V transpose: qkv v-part -> VT [bh][64 d][2048 t] bf16 ----------
__global__ __launch_bounds__(256) void vtr_kernel(const unsigned short* __restrict__ qkv,
                                                  unsigned short* __restrict__ vt) {
  __shared__ unsigned short tile[64][72];
  int bh = blockIdx.y, t0 = blockIdx.x * 64;
  int b = bh >> 4, h = bh & 15;
  int r = threadIdx.x >> 3, sl = threadIdx.x & 7;
#pragma unroll
  for (int half = 0; half < 2; ++half) {
    int rr = r + half * 32;
    bf16x8 v = *(const bf16x8*)(qkv + (size_t)(b * TSEQ + t0 + rr) * 3072 + 2048 + h * 64 + sl * 8);
    *(bf16x8*)&tile[rr][sl * 8] = v;  // row stride 144B (16B-aligned)
  }
  __syncthreads();
#pragma unroll
  for (int half = 0; half < 2; ++half) {
    int d = r + half * 32;
    bf16x8 o;
#pragma unroll
    for (int j = 0; j < 8; ++j) o[j] = (short)tile[sl * 8 + j][d];
    *(bf16x8*)(vt + ((size_t)bh * 64 + d) * TSEQ + t0 + sl * 8) = o;
  }
}

// ---------- causal flash attention v5: paired q-tiles for load balance ----------
// Block handles q-tiles (qb_lo=pair, qb_hi=31-pair) of one (b,h): compute-tiles
// per wave = (32-pair)+(pair+1) = 33, uniform across all 512 blocks. Both
// q-tiles share each staged K/V tile. 4 waves x 16 q-rows per q-tile; KVBLK=64;
// swizzled LDS; full online-softmax; deferred final l-reduce.
__global__ __launch_bounds__(256) void attn_kernel(const unsigned short* __restrict__ qkv,
                                                   const unsigned short* __restrict__ vt,
                                                   unsigned short* __restrict__ attn_out) {
  __shared__ alignas(16) unsigned short Ks[2][64 * 64];     // [k][d] swz
  __shared__ alignas(16) unsigned short Vs[2][64 * 64];     // [d][k] swz
  __shared__ alignas(16) unsigned short Ps[4][2][16 * 64];  // per-wave, per-qtile
  int tid = threadIdx.x, w = tid >> 6, l = tid & 63, g = l >> 4, c = l & 15;
  int bid = blockIdx.x;
  int pair = bid & 15;
  int bh = bid >> 4, b = bh >> 4, h = bh & 15;
  int qbh = 31 - pair, qbl = pair;
  int qwh = qbh * 64 + w * 16;
  int qwl = qbl * 64 + w * 16;

  // Q fragments for both q-tiles: rows qw + c, d-slices s*32 + g*8
  bf16x8 qfh[2], qfl[2];
#pragma unroll
  for (int s = 0; s < 2; ++s) {
    qfh[s] = *(const bf16x8*)(qkv + (size_t)(b * TSEQ + qwh + c) * 3072 + h * 64 + s * 32 + g * 8);
    qfl[s] = *(const bf16x8*)(qkv + (size_t)(b * TSEQ + qwl + c) * 3072 + h * 64 + s * 32 + g * 8);
  }

  f32x4 oh[4], ol[4];
  float mh[4], lh[4], ml[4], ll[4];
#pragma unroll
  for (int dc = 0; dc < 4; ++dc)
#pragma unroll
    for (int e = 0; e < 4; ++e) { oh[dc][e] = 0.0f; ol[dc][e] = 0.0f; }
#pragma unroll
  for (int r = 0; r < 4; ++r) { mh[r] = -1e30f; lh[r] = 0.0f; ml[r] = -1e30f; ll[r] = 0.0f; }

  int ntile = qbh + 1;
  int sr = tid >> 3, ss = tid & 7;  // staging: 32 rows x 8 slots, 2 halves
  bf16x8 kreg[2], vreg[2];

#define LOADT(K0)                                                                       \
  {                                                                                     \
    _Pragma("unroll") for (int hf = 0; hf < 2; ++hf) {                                  \
      int rr = sr + hf * 32;                                                            \
      kreg[hf] = *(const bf16x8*)(qkv + (size_t)(b * TSEQ + (K0) + rr) * 3072 + 1024 +  \
                                  h * 64 + ss * 8);                                     \
      vreg[hf] = *(const bf16x8*)(vt + ((size_t)bh * 64 + rr) * TSEQ + (K0) + ss * 8);  \
    }                                                                                   \
  }
#define WRITET(BUF)                                                                     \
  {                                                                                     \
    _Pragma("unroll") for (int hf = 0; hf < 2; ++hf) {                                  \
      int rr = sr + hf * 32;                                                            \
      unsigned off = (unsigned)(rr * 128 + ss * 16) ^ (unsigned)((rr & 7) << 4);        \
      *(bf16x8*)((char*)Ks[BUF] + off) = kreg[hf];                                      \
      *(bf16x8*)((char*)Vs[BUF] + off) = vreg[hf];                                      \
    }                                                                                   \
  }
// one q-tile's QK -> softmax -> P -> PV against the staged tile
#define COMPQ(QF, O, MR, LP, QW, PSL)                                                   \
  {                                                                                     \
    f32x4 s_[4];                                                                        \
    _Pragma("unroll") for (int ni = 0; ni < 4; ++ni) {                                  \
      int krow_ = ni * 16 + c;                                                          \
      unsigned swz_ = (unsigned)((c & 7) << 4);                                         \
      bf16x8 kf0_ = *(const bf16x8*)(Kb + (((unsigned)(krow_ * 128) + g * 16) ^ swz_)); \
      bf16x8 kf1_ = *(const bf16x8*)(Kb + (((unsigned)(krow_ * 128) + 64 + g * 16) ^ swz_)); \
      f32x4 a_;                                                                         \
      _Pragma("unroll") for (int e = 0; e < 4; ++e) a_[e] = 0.0f;                       \
      a_ = __builtin_amdgcn_mfma_f32_16x16x32_bf16(QF[0], kf0_, a_, 0, 0, 0);           \
      a_ = __builtin_amdgcn_mfma_f32_16x16x32_bf16(QF[1], kf1_, a_, 0, 0, 0);           \
      s_[ni] = a_;                                                                      \
    }                                                                                   \
    bool full_ = (k0 + 63 <= (QW));                                                     \
    _Pragma("unroll") for (int r = 0; r < 4; ++r) {                                     \
      int qg_ = (QW) + g * 4 + r;                                                       \
      float pm_[4];                                                                     \
      _Pragma("unroll") for (int ni = 0; ni < 4; ++ni) {                                \
        float v_ = s_[ni][r] * 0.125f;                                                  \
        if (!full_) {                                                                   \
          int kg_ = k0 + ni * 16 + c;                                                   \
          v_ = (kg_ <= qg_) ? v_ : -1e30f;                                              \
        }                                                                               \
        pm_[ni] = v_;                                                                   \
      }                                                                                 \
      float mx_ = fmaxf(fmaxf(pm_[0], pm_[1]), fmaxf(pm_[2], pm_[3]));                  \
      mx_ = fmaxf(mx_, __shfl_xor(mx_, 1, 64));                                         \
      mx_ = fmaxf(mx_, __shfl_xor(mx_, 2, 64));                                         \
      mx_ = fmaxf(mx_, __shfl_xor(mx_, 4, 64));                                         \
      mx_ = fmaxf(mx_, __shfl_xor(mx_, 8, 64));                                         \
      float mnew_ = fmaxf(MR[r], mx_);                                                  \
      float scale_ = __expf(MR[r] - mnew_);                                             \
      MR[r] = mnew_;                                                                    \
      float p_[4], rs_ = 0.0f;                                                          \
      _Pragma("unroll") for (int ni = 0; ni < 4; ++ni) {                                \
        p_[ni] = __expf(pm_[ni] - mnew_); rs_ += p_[ni];                                \
      }                                                                                 \
      LP[r] = LP[r] * scale_ + rs_;                                                     \
      _Pragma("unroll") for (int dc = 0; dc < 4; ++dc) O[dc][r] *= scale_;              \
      int prow_ = g * 4 + r;                                                            \
      unsigned pswz_ = (unsigned)((prow_ & 7) << 4);                                    \
      _Pragma("unroll") for (int ni = 0; ni < 4; ++ni)                                  \
        *(unsigned short*)((char*)Ps[w][PSL] +                                          \
            (((unsigned)(prow_ * 128 + (ni * 16 + c) * 2)) ^ pswz_)) = f2bf(p_[ni]);    \
    }                                                                                   \
    asm volatile("s_waitcnt lgkmcnt(0)" ::: "memory");                                  \
    unsigned swz2_ = (unsigned)((c & 7) << 4);                                          \
    _Pragma("unroll") for (int kc = 0; kc < 2; ++kc) {                                  \
      bf16x8 pf_ = *(const bf16x8*)((const char*)Ps[w][PSL] +                           \
                    (((unsigned)(c * 128 + kc * 64 + g * 16)) ^ swz2_));                \
      _Pragma("unroll") for (int dc = 0; dc < 4; ++dc) {                                \
        bf16x8 vf_ = *(const bf16x8*)(Vb +                                              \
                      (((unsigned)((dc * 16 + c) * 128 + kc * 64 + g * 16)) ^ swz2_));  \
        O[dc] = __builtin_amdgcn_mfma_f32_16x16x32_bf16(pf_, vf_, O[dc], 0, 0, 0);      \
      }                                                                                 \
    }                                                                                   \
  }

  LOADT(0);
  WRITET(0);
  __syncthreads();

  for (int t = 0; t < ntile; ++t) {
    int k0 = t << 6, cur = t & 1;
    if (t + 1 < ntile) LOADT((t + 1) << 6);

    {
      const char* Kb = (const char*)Ks[cur];
      const char* Vb = (const char*)Vs[cur];
      // hi q-tile: needed for every staged tile
      COMPQ(qfh, oh, mh, lh, qwh, 0);
      // lo q-tile: only first (pair+1) tiles
      if (k0 <= qwl + 15) COMPQ(qfl, ol, ml, ll, qwl, 1);
    }

    if (t + 1 < ntile) {
      WRITET(cur ^ 1);
      __syncthreads();
    }
  }

#pragma unroll
  for (int r = 0; r < 4; ++r) {
    float lrh = lh[r], lrl = ll[r];
    lrh += __shfl_xor(lrh, 1, 64);
    lrh += __shfl_xor(lrh, 2, 64);
    lrh += __shfl_xor(lrh, 4, 64);
    lrh += __shfl_xor(lrh, 8, 64);
    lrl += __shfl_xor(lrl, 1, 64);
    lrl += __shfl_xor(lrl, 2, 64);
    lrl += __shfl_xor(lrl, 4, 64);
    lrl += __shfl_xor(lrl, 8, 64);
    float invh = 1.0f / lrh, invl = 1.0f / lrl;
    size_t rowh = (size_t)b * TSEQ + qwh + g * 4 + r;
    size_t rowl = (size_t)b * TSEQ + qwl + g * 4 + r;
    unsigned short* oph = attn_out + rowh * 1024 + h * 64 + c;
    unsigned short* opl = attn_out + rowl * 1024 + h * 64 + c;
#pragma unroll
    for (int dc = 0; dc < 4; ++dc) {
      oph[dc * 16] = f2bf(oh[dc][r] * invh);
      opl[dc * 16] = f2bf(ol[dc][r] * invl);
    }
  }
#undef LOADT
#undef WRITET
#undef COMPQ
}

extern "C" void kernel_launch(void* const* d_in, const int* in_sizes, int n_in,
                              void* d_out, int out_size, void* d_ws, size_t ws_size,
                              hipStream_t stream) {
  const float* x    = (const float*)d_in[0];
  const float* ln1w = (const float*)d_in[1];
  const float* ln2w = (const float*)d_in[2];
  const float* Wq   = (const float*)d_in[3];
  const float* bq   = (const float*)d_in[4];
  const float* Wk   = (const float*)d_in[5];
  const float* bk   = (const float*)d_in[6];
  const float* Wv   = (const float*)d_in[7];
  const float* bv   = (const float*)d_in[8];
  const float* Wo   = (const float*)d_in[9];
  const float* bo   = (const float*)d_in[10];
  const float* Wup  = (const float*)d_in[11];
  const float* bup  = (const float*)d_in[12];
  const float* Wdn  = (const float*)d_in[13];
  const float* bdn  = (const float*)d_in[14];

  char* ws = (char*)d_ws;
  unsigned short* xn1   = (unsigned short*)(ws + 0);              // 8 MB [4096][1024] bf16
  unsigned short* vtb   = (unsigned short*)(ws + 0);              // 8 MB [32][64][2048] bf16 (aliases xn1, dead by then)
  unsigned short* qkv   = (unsigned short*)(ws + (8ull << 20));   // 24 MB [4096][3072] bf16
  unsigned short* gbuf  = (unsigned short*)(ws + 0);              // 32 MB, aliases vtb+qkv (both dead)
  unsigned short* attn  = (unsigned short*)(ws + (32ull << 20));  // 8 MB [4096][1024] bf16
  float*          x2    = (float*)(ws + (40ull << 20));           // 16 MB [4096][1024] f32
  unsigned short* h2    = (unsigned short*)(ws + (56ull << 20));  // 8 MB
  unsigned short* WqkvT = (unsigned short*)(ws + (64ull << 20));  // 6 MB [3072][1024]
  unsigned short* WoT   = (unsigned short*)(ws + (70ull << 20));  // 2 MB [1024][1024]
  unsigned short* WupT  = (unsigned short*)(ws + (72ull << 20));  // 8 MB [4096][1024]
  unsigned short* WdnT  = (unsigned short*)(ws + (80ull << 20));  // 8 MB [1024][4096]
  float*          bqkv  = (float*)(ws + (88ull << 20));           // 12 KB [3072]

  dim3 blk(256);
  dim3 blk512(512);
  // weight transposes (fp32 -> bf16 W^T)
  tr_kernel<<<dim3(32, 32), blk, 0, stream>>>(Wq, WqkvT, 1024, 1024);
  tr_kernel<<<dim3(32, 32), blk, 0, stream>>>(Wk, WqkvT + 1024 * 1024, 1024, 1024);
  tr_kernel<<<dim3(32, 32), blk, 0, stream>>>(Wv, WqkvT + 2 * 1024 * 1024, 1024, 1024);
  tr_kernel<<<dim3(32, 32), blk, 0, stream>>>(Wo, WoT, 1024, 1024);
  tr_kernel<<<dim3(128, 32), blk, 0, stream>>>(Wup, WupT, 1024, 4096);
  tr_kernel<<<dim3(32, 128), blk, 0, stream>>>(Wdn, WdnT, 4096, 1024);
  concat3_kernel<<<dim3(4), blk, 0, stream>>>(bq, bk, bv, bqkv, 1024);

  // x -> rmsnorm -> qkv (256^2 dbuf tile: grid 12x16 = 192 blocks, %8==0)
  rmsnorm_kernel<<<dim3(NROW), blk, 0, stream>>>(x, ln1w, xn1);
  gemm_db256<0><<<dim3(12, 16), blk512, 0, stream>>>(xn1, WqkvT, bqkv, nullptr, qkv, NROW, 3072, 1024);

  // V transpose then attention (paired causal tiles: 512 uniform blocks)
  vtr_kernel<<<dim3(32, 32), blk, 0, stream>>>(qkv, vtb);
  attn_kernel<<<dim3(512), blk, 0, stream>>>(qkv, vtb, attn);

  // x2 = x + attn @ Wo + bo (narrow N=1024: 128^2 dbuf path)
  gemm_bt<1><<<dim3(8, 32), blk, 0, stream>>>(attn, WoT, bo, x, x2, NROW, 1024, 1024);

  // mlp
  rmsnorm_kernel<<<dim3(NROW), blk, 0, stream>>>(x2, ln2w, h2);
  gemm_db256<2><<<dim3(16, 16), blk512, 0, stream>>>(h2, WupT, bup, nullptr, gbuf, NROW, 4096, 1024);
  gemm_bt<1><<<dim3(8, 32), blk, 0, stream>>>(gbuf, WdnT, bdn, x2, d_out, NROW, 1024, 4096);
}

// Round 11
// 417.022 us; speedup vs baseline: 1.2164x; 1.0027x over previous
//
#include <hip/hip_runtime.h>
#include <cmath>

#define DM   1024
#define HDS  16
#define DH   64
#define DMLP 4096
#define TSEQ 2048
#define NROW 4096   // B*T = 2*2048

typedef short bf16x8 __attribute__((ext_vector_type(8)));
typedef float f32x4 __attribute__((ext_vector_type(4)));

__device__ __forceinline__ unsigned short f2bf(float f) {
  union { float f; unsigned u; } v; v.f = f;
  unsigned r = v.u + 0x7fffu + ((v.u >> 16) & 1u);
  return (unsigned short)(r >> 16);
}

__device__ __forceinline__ void gload_lds16(const void* g, void* l) {
  __builtin_amdgcn_global_load_lds(
      (const __attribute__((address_space(1))) unsigned int*)g,
      (__attribute__((address_space(3))) unsigned int*)l, 16, 0, 0);
}

// ---------- transpose fp32 [K][N] -> bf16 [N][K] ----------
__global__ __launch_bounds__(256) void tr_kernel(const float* __restrict__ in,
                                                 unsigned short* __restrict__ out,
                                                 int K, int N) {
  __shared__ unsigned short tile[32][33];
  int n0 = blockIdx.x * 32, k0 = blockIdx.y * 32;
  int tx = threadIdx.x & 31, ty = threadIdx.x >> 5;
#pragma unroll
  for (int j = 0; j < 4; ++j) {
    int k = ty + j * 8;
    tile[k][tx] = f2bf(in[(size_t)(k0 + k) * N + n0 + tx]);
  }
  __syncthreads();
#pragma unroll
  for (int j = 0; j < 4; ++j) {
    int n = ty + j * 8;
    out[(size_t)(n0 + n) * K + k0 + tx] = tile[tx][n];
  }
}

__global__ void concat3_kernel(const float* __restrict__ a, const float* __restrict__ b,
                               const float* __restrict__ c, float* __restrict__ out, int n) {
  int i = blockIdx.x * 256 + threadIdx.x;
  if (i < n) { out[i] = a[i]; out[n + i] = b[i]; out[2 * n + i] = c[i]; }
}

// ---------- rmsnorm fp32 [NROW][DM] -> bf16 ----------
__global__ __launch_bounds__(256) void rmsnorm_kernel(const float* __restrict__ x,
                                                      const float* __restrict__ w,
                                                      unsigned short* __restrict__ out) {
  int row = blockIdx.x;
  int t = threadIdx.x;
  const float4* xr = (const float4*)(x + (size_t)row * DM);
  float4 v = xr[t];
  float ss = v.x * v.x + v.y * v.y + v.z * v.z + v.w * v.w;
#pragma unroll
  for (int m = 1; m < 64; m <<= 1) ss += __shfl_xor(ss, m, 64);
  __shared__ float sred[4];
  if ((t & 63) == 0) sred[t >> 6] = ss;
  __syncthreads();
  ss = sred[0] + sred[1] + sred[2] + sred[3];
  float norm = rsqrtf(ss * (1.0f / DM) + 1e-6f);
  float4 wv = ((const float4*)w)[t];
  ushort4 o;
  o.x = f2bf(v.x * norm * wv.x);
  o.y = f2bf(v.y * norm * wv.y);
  o.z = f2bf(v.z * norm * wv.z);
  o.w = f2bf(v.w * norm * wv.w);
  ((ushort4*)out)[(size_t)row * (DM / 4) + t] = o;
}

// ---------- GEMM 128x128 tile, BK=32, dbuf + bank-swizzle ----------
// EPI: 0 = +bias -> bf16 ; 1 = +bias + res -> f32 ; 2 = +bias, exact gelu -> bf16
// Bank swizzle (rule #21 involution): 64B rows -> bank-set bits {row&1, slot}.
// slot ^= (row>>1)&3 spreads 16 lanes over all 8 bank-sets (2/set = free).
// Source side: gslot = (tid&3) ^ ((tid>>3)&3); read side: (l>>4) ^ (((l&15)>>1)&3).
template <int EPI>
__global__ __launch_bounds__(256) void gemm_bt(const unsigned short* __restrict__ A,
                                               const unsigned short* __restrict__ BT,
                                               const float* __restrict__ bias,
                                               const float* __restrict__ res,
                                               void* __restrict__ outp,
                                               int M, int N, int K) {
  __shared__ alignas(16) unsigned short As[2][128 * 32];
  __shared__ alignas(16) unsigned short Bs[2][128 * 32];
  int tid = threadIdx.x;
  int w = tid >> 6, l = tid & 63;
  unsigned nx = gridDim.x;
  unsigned bidl = blockIdx.y * nx + blockIdx.x;
  unsigned nwg = nx * gridDim.y;
  unsigned cpx = nwg >> 3;
  unsigned sb = (bidl & 7) * cpx + (bidl >> 3);
  int m0 = (int)(sb / nx) * 128, n0 = (int)(sb % nx) * 128;
  int wr = w >> 1, wc = w & 1;
  f32x4 acc[4][4];
#pragma unroll
  for (int i = 0; i < 4; ++i)
#pragma unroll
    for (int j = 0; j < 4; ++j)
#pragma unroll
      for (int e = 0; e < 4; ++e) acc[i][j][e] = 0.0f;

  int nk = K >> 5;
  int arow = tid >> 2;                              // 64 rows per half-tile
  int gslot = (tid & 3) ^ ((tid >> 3) & 3);         // pre-swizzled source 16B slot

#define STG128(BUF, KT)                                                            \
  {                                                                                \
    _Pragma("unroll") for (int i = 0; i < 2; ++i) {                                \
      int row = i * 64 + arow;                                                     \
      gload_lds16(A + (size_t)(m0 + row) * K + (size_t)(KT) * 32 + gslot * 8,      \
                  (char*)As[BUF] + i * 4096 + w * 1024);                           \
      gload_lds16(BT + (size_t)(n0 + row) * K + (size_t)(KT) * 32 + gslot * 8,     \
                  (char*)Bs[BUF] + i * 4096 + w * 1024);                           \
    }                                                                              \
  }

  int rslot = (l >> 4) ^ (((l & 15) >> 1) & 3);     // swizzled read slot
  STG128(0, 0);
  __syncthreads();
  int cur = 0;
  for (int kt = 0; kt < nk; ++kt) {
    if (kt + 1 < nk) STG128(cur ^ 1, kt + 1);
    bf16x8 af[4], bfr[4];
#pragma unroll
    for (int mt = 0; mt < 4; ++mt)
      af[mt] = *(const bf16x8*)((const char*)As[cur] +
                (size_t)(wr * 64 + mt * 16 + (l & 15)) * 64 + rslot * 16);
#pragma unroll
    for (int nt = 0; nt < 4; ++nt)
      bfr[nt] = *(const bf16x8*)((const char*)Bs[cur] +
                 (size_t)(wc * 64 + nt * 16 + (l & 15)) * 64 + rslot * 16);
#pragma unroll
    for (int mt = 0; mt < 4; ++mt)
#pragma unroll
      for (int nt = 0; nt < 4; ++nt)
        acc[mt][nt] = __builtin_amdgcn_mfma_f32_16x16x32_bf16(af[mt], bfr[nt], acc[mt][nt], 0, 0, 0);
    __syncthreads();  // drains vmcnt(0)+lgkmcnt(0) then barrier
    cur ^= 1;
  }
#undef STG128

  int g = l >> 4, c = l & 15;
#pragma unroll
  for (int mt = 0; mt < 4; ++mt) {
#pragma unroll
    for (int nt = 0; nt < 4; ++nt) {
#pragma unroll
      for (int r = 0; r < 4; ++r) {
        int m = m0 + wr * 64 + mt * 16 + g * 4 + r;
        int n = n0 + wc * 64 + nt * 16 + c;
        float v = acc[mt][nt][r] + bias[n];
        if (EPI == 2) v = 0.5f * v * (1.0f + erff(v * 0.70710678118654752f));
        if (EPI == 1) {
          v += res[(size_t)m * N + n];
          ((float*)outp)[(size_t)m * N + n] = v;
        } else {
          ((unsigned short*)outp)[(size_t)m * N + n] = f2bf(v);
        }
      }
    }
  }
}

// ---------- GEMM 256x256, BK=64, 8 waves, double-buffered + T2 swizzle ----------
// LDS dest linear (global_load_lds requirement); bank swizzle achieved by
// inverse-permuting the GLOBAL source 16B-slot (slot ^= row&7) and applying the
// same XOR on the ds_read side (rule #21: both-sides-or-neither involution).
template <int EPI>
__global__ __launch_bounds__(512) void gemm_db256(const unsigned short* __restrict__ A,
                                                  const unsigned short* __restrict__ BT,
                                                  const float* __restrict__ bias,
                                                  const float* __restrict__ res,
                                                  void* __restrict__ outp,
                                                  int M, int N, int K) {
  __shared__ alignas(16) unsigned short As[2][256 * 64];  // 2 x 32 KB
  __shared__ alignas(16) unsigned short Bs[2][256 * 64];  // 2 x 32 KB
  int tid = threadIdx.x;
  int w = tid >> 6, l = tid & 63;
  int wr = w >> 2, wc = w & 3;  // 2M x 4N waves
  unsigned nx = gridDim.x;
  unsigned bidl = blockIdx.y * nx + blockIdx.x;
  unsigned nwg = nx * gridDim.y;
  unsigned cpx = nwg >> 3;  // grid must be %8==0
  unsigned sb = (bidl & 7) * cpx + (bidl >> 3);
  int m0 = (int)(sb / nx) * 256, n0 = (int)(sb % nx) * 256;

  f32x4 acc[8][4];
#pragma unroll
  for (int i = 0; i < 8; ++i)
#pragma unroll
    for (int j = 0; j < 4; ++j)
#pragma unroll
      for (int e = 0; e < 4; ++e) acc[i][j][e] = 0.0f;

  int nk = K >> 6;
  int srow = tid >> 3, sslot = tid & 7;  // 64 rows x 8 slots per stage inst
  int gslot = sslot ^ (srow & 7);        // pre-swizzled source slot
  int c = l & 15, g = l >> 4;

#define STG256(BUF, KT)                                                            \
  {                                                                                \
    _Pragma("unroll") for (int i = 0; i < 4; ++i) {                                \
      int row = i * 64 + srow;                                                     \
      gload_lds16(A + (size_t)(m0 + row) * K + (size_t)(KT) * 64 + gslot * 8,      \
                  (char*)As[BUF] + i * 8192 + w * 1024);                           \
      gload_lds16(BT + (size_t)(n0 + row) * K + (size_t)(KT) * 64 + gslot * 8,     \
                  (char*)Bs[BUF] + i * 8192 + w * 1024);                           \
    }                                                                              \
  }

  STG256(0, 0);
  __syncthreads();
  int cur = 0;
  for (int kt = 0; kt < nk; ++kt) {
    if (kt + 1 < nk) STG256(cur ^ 1, kt + 1);
#pragma unroll
    for (int ks = 0; ks < 2; ++ks) {
      bf16x8 bfr[4];
#pragma unroll
      for (int nt = 0; nt < 4; ++nt) {
        int brow = wc * 64 + nt * 16 + c;
        unsigned bslot = (unsigned)((ks * 4 + g) ^ (brow & 7));
        bfr[nt] = *(const bf16x8*)((const char*)Bs[cur] + (size_t)brow * 128 + bslot * 16);
      }
#pragma unroll
      for (int mt = 0; mt < 8; ++mt) {
        int arow2 = wr * 128 + mt * 16 + c;
        unsigned aslot2 = (unsigned)((ks * 4 + g) ^ (arow2 & 7));
        bf16x8 af = *(const bf16x8*)((const char*)As[cur] + (size_t)arow2 * 128 + aslot2 * 16);
#pragma unroll
        for (int nt = 0; nt < 4; ++nt)
          acc[mt][nt] = __builtin_amdgcn_mfma_f32_16x16x32_bf16(af, bfr[nt], acc[mt][nt], 0, 0, 0);
      }
    }
    __syncthreads();  // drains vmcnt(0)+lgkmcnt(0) then barrier
    cur ^= 1;
  }
#undef STG256

#pragma unroll
  for (int mt = 0; mt < 8; ++mt) {
#pragma unroll
    for (int nt = 0; nt < 4; ++nt) {
#pragma unroll
      for (int r = 0; r < 4; ++r) {
        int m = m0 + wr * 128 + mt * 16 + g * 4 + r;
        int n = n0 + wc * 64 + nt * 16 + c;
        float v = acc[mt][nt][r] + bias[n];
        if (EPI == 2) v = 0.5f * v * (1.0f + erff(v * 0.70710678118654752f));
        if (EPI == 1) {
          v += res[(size_t)m * N + n];
          ((float*)outp)[(size_t)m * N + n] = v;
        } else {
          ((unsigned short*)outp)[(size_t)m * N + n] = f2bf(v);
        }
      }
    }
  }
}

// ---------- V transpose: qkv v-part -> VT [bh][64 d][2048 t] bf16 ----------
__global__ __launch_bounds__(256) void vtr_kernel(const unsigned short* __restrict__ qkv,
                                                  unsigned short* __restrict__ vt) {
  __shared__ unsigned short tile[64][72];
  int bh = blockIdx.y, t0 = blockIdx.x * 64;
  int b = bh >> 4, h = bh & 15;
  int r = threadIdx.x >> 3, sl = threadIdx.x & 7;
#pragma unroll
  for (int half = 0; half < 2; ++half) {
    int rr = r + half * 32;
    bf16x8 v = *(const bf16x8*)(qkv + (size_t)(b * TSEQ + t0 + rr) * 3072 + 2048 + h * 64 + sl * 8);
    *(bf16x8*)&tile[rr][sl * 8] = v;  // row stride 144B (16B-aligned)
  }
  __syncthreads();
#pragma unroll
  for (int half = 0; half < 2; ++half) {
    int d = r + half * 32;
    bf16x8 o;
#pragma unroll
    for (int j = 0; j < 8; ++j) o[j] = (short)tile[sl * 8 + j][d];
    *(bf16x8*)(vt + ((size_t)bh * 64 + d) * TSEQ + t0 + sl * 8) = o;
  }
}

// ---------- causal flash attention v5: paired q-tiles for load balance ----------
// Block handles q-tiles (qb_lo=pair, qb_hi=31-pair) of one (b,h): compute-tiles
// per wave = (32-pair)+(pair+1) = 33, uniform across all 512 blocks. Both
// q-tiles share each staged K/V tile. 4 waves x 16 q-rows per q-tile; KVBLK=64;
// swizzled LDS; full online-softmax; deferred final l-reduce.
__global__ __launch_bounds__(256) void attn_kernel(const unsigned short* __restrict__ qkv,
                                                   const unsigned short* __restrict__ vt,
                                                   unsigned short* __restrict__ attn_out) {
  __shared__ alignas(16) unsigned short Ks[2][64 * 64];     // [k][d] swz
  __shared__ alignas(16) unsigned short Vs[2][64 * 64];     // [d][k] swz
  __shared__ alignas(16) unsigned short Ps[4][2][16 * 64];  // per-wave, per-qtile
  int tid = threadIdx.x, w = tid >> 6, l = tid & 63, g = l >> 4, c = l & 15;
  int bid = blockIdx.x;
  int pair = bid & 15;
  int bh = bid >> 4, b = bh >> 4, h = bh & 15;
  int qbh = 31 - pair, qbl = pair;
  int qwh = qbh * 64 + w * 16;
  int qwl = qbl * 64 + w * 16;

  // Q fragments for both q-tiles: rows qw + c, d-slices s*32 + g*8
  bf16x8 qfh[2], qfl[2];
#pragma unroll
  for (int s = 0; s < 2; ++s) {
    qfh[s] = *(const bf16x8*)(qkv + (size_t)(b * TSEQ + qwh + c) * 3072 + h * 64 + s * 32 + g * 8);
    qfl[s] = *(const bf16x8*)(qkv + (size_t)(b * TSEQ + qwl + c) * 3072 + h * 64 + s * 32 + g * 8);
  }

  f32x4 oh[4], ol[4];
  float mh[4], lh[4], ml[4], ll[4];
#pragma unroll
  for (int dc = 0; dc < 4; ++dc)
#pragma unroll
    for (int e = 0; e < 4; ++e) { oh[dc][e] = 0.0f; ol[dc][e] = 0.0f; }
#pragma unroll
  for (int r = 0; r < 4; ++r) { mh[r] = -1e30f; lh[r] = 0.0f; ml[r] = -1e30f; ll[r] = 0.0f; }

  int ntile = qbh + 1;
  int sr = tid >> 3, ss = tid & 7;  // staging: 32 rows x 8 slots, 2 halves
  bf16x8 kreg[2], vreg[2];

#define LOADT(K0)                                                                       \
  {                                                                                     \
    _Pragma("unroll") for (int hf = 0; hf < 2; ++hf) {                                  \
      int rr = sr + hf * 32;                                                            \
      kreg[hf] = *(const bf16x8*)(qkv + (size_t)(b * TSEQ + (K0) + rr) * 3072 + 1024 +  \
                                  h * 64 + ss * 8);                                     \
      vreg[hf] = *(const bf16x8*)(vt + ((size_t)bh * 64 + rr) * TSEQ + (K0) + ss * 8);  \
    }                                                                                   \
  }
#define WRITET(BUF)                                                                     \
  {                                                                                     \
    _Pragma("unroll") for (int hf = 0; hf < 2; ++hf) {                                  \
      int rr = sr + hf * 32;                                                            \
      unsigned off = (unsigned)(rr * 128 + ss * 16) ^ (unsigned)((rr & 7) << 4);        \
      *(bf16x8*)((char*)Ks[BUF] + off) = kreg[hf];                                      \
      *(bf16x8*)((char*)Vs[BUF] + off) = vreg[hf];                                      \
    }                                                                                   \
  }
// one q-tile's QK -> softmax -> P -> PV against the staged tile
#define COMPQ(QF, O, MR, LP, QW, PSL)                                                   \
  {                                                                                     \
    f32x4 s_[4];                                                                        \
    _Pragma("unroll") for (int ni = 0; ni < 4; ++ni) {                                  \
      int krow_ = ni * 16 + c;                                                          \
      unsigned swz_ = (unsigned)((c & 7) << 4);                                         \
      bf16x8 kf0_ = *(const bf16x8*)(Kb + (((unsigned)(krow_ * 128) + g * 16) ^ swz_)); \
      bf16x8 kf1_ = *(const bf16x8*)(Kb + (((unsigned)(krow_ * 128) + 64 + g * 16) ^ swz_)); \
      f32x4 a_;                                                                         \
      _Pragma("unroll") for (int e = 0; e < 4; ++e) a_[e] = 0.0f;                       \
      a_ = __builtin_amdgcn_mfma_f32_16x16x32_bf16(QF[0], kf0_, a_, 0, 0, 0);           \
      a_ = __builtin_amdgcn_mfma_f32_16x16x32_bf16(QF[1], kf1_, a_, 0, 0, 0);           \
      s_[ni] = a_;                                                                      \
    }                                                                                   \
    bool full_ = (k0 + 63 <= (QW));                                                     \
    _Pragma("unroll") for (int r = 0; r < 4; ++r) {                                     \
      int qg_ = (QW) + g * 4 + r;                                                       \
      float pm_[4];                                                                     \
      _Pragma("unroll") for (int ni = 0; ni < 4; ++ni) {                                \
        float v_ = s_[ni][r] * 0.125f;                                                  \
        if (!full_) {                                                                   \
          int kg_ = k0 + ni * 16 + c;                                                   \
          v_ = (kg_ <= qg_) ? v_ : -1e30f;                                              \
        }                                                                               \
        pm_[ni] = v_;                                                                   \
      }                                                                                 \
      float mx_ = fmaxf(fmaxf(pm_[0], pm_[1]), fmaxf(pm_[2], pm_[3]));                  \
      mx_ = fmaxf(mx_, __shfl_xor(mx_, 1, 64));                                         \
      mx_ = fmaxf(mx_, __shfl_xor(mx_, 2, 64));                                         \
      mx_ = fmaxf(mx_, __shfl_xor(mx_, 4, 64));                                         \
      mx_ = fmaxf(mx_, __shfl_xor(mx_, 8, 64));                                         \
      float mnew_ = fmaxf(MR[r], mx_);                                                  \
      float scale_ = __expf(MR[r] - mnew_);                                             \
      MR[r] = mnew_;                                                                    \
      float p_[4], rs_ = 0.0f;                                                          \
      _Pragma("unroll") for (int ni = 0; ni < 4; ++ni) {                                \
        p_[ni] = __expf(pm_[ni] - mnew_); rs_ += p_[ni];                                \
      }                                                                                 \
      LP[r] = LP[r] * scale_ + rs_;                                                     \
      _Pragma("unroll") for (int dc = 0; dc < 4; ++dc) O[dc][r] *= scale_;              \
      int prow_ = g * 4 + r;                                                            \
      unsigned pswz_ = (unsigned)((prow_ & 7) << 4);                                    \
      _Pragma("unroll") for (int ni = 0; ni < 4; ++ni)                                  \
        *(unsigned short*)((char*)Ps[w][PSL] +                                          \
            (((unsigned)(prow_ * 128 + (ni * 16 + c) * 2)) ^ pswz_)) = f2bf(p_[ni]);    \
    }                                                                                   \
    asm volatile("s_waitcnt lgkmcnt(0)" ::: "memory");                                  \
    unsigned swz2_ = (unsigned)((c & 7) << 4);                                          \
    _Pragma("unroll") for (int kc = 0; kc < 2; ++kc) {                                  \
      bf16x8 pf_ = *(const bf16x8*)((const char*)Ps[w][PSL] +                           \
                    (((unsigned)(c * 128 + kc * 64 + g * 16)) ^ swz2_));                \
      _Pragma("unroll") for (int dc = 0; dc < 4; ++dc) {                                \
        bf16x8 vf_ = *(const bf16x8*)(Vb +                                              \
                      (((unsigned)((dc * 16 + c) * 128 + kc * 64 + g * 16)) ^ swz2_));  \
        O[dc] = __builtin_amdgcn_mfma_f32_16x16x32_bf16(pf_, vf_, O[dc], 0, 0, 0);      \
      }                                                                                 \
    }                                                                                   \
  }

  LOADT(0);
  WRITET(0);
  __syncthreads();

  for (int t = 0; t < ntile; ++t) {
    int k0 = t << 6, cur = t & 1;
    if (t + 1 < ntile) LOADT((t + 1) << 6);

    {
      const char* Kb = (const char*)Ks[cur];
      const char* Vb = (const char*)Vs[cur];
      // hi q-tile: needed for every staged tile
      COMPQ(qfh, oh, mh, lh, qwh, 0);
      // lo q-tile: only first (pair+1) tiles
      if (k0 <= qwl + 15) COMPQ(qfl, ol, ml, ll, qwl, 1);
    }

    if (t + 1 < ntile) {
      WRITET(cur ^ 1);
      __syncthreads();
    }
  }

#pragma unroll
  for (int r = 0; r < 4; ++r) {
    float lrh = lh[r], lrl = ll[r];
    lrh += __shfl_xor(lrh, 1, 64);
    lrh += __shfl_xor(lrh, 2, 64);
    lrh += __shfl_xor(lrh, 4, 64);
    lrh += __shfl_xor(lrh, 8, 64);
    lrl += __shfl_xor(lrl, 1, 64);
    lrl += __shfl_xor(lrl, 2, 64);
    lrl += __shfl_xor(lrl, 4, 64);
    lrl += __shfl_xor(lrl, 8, 64);
    float invh = 1.0f / lrh, invl = 1.0f / lrl;
    size_t rowh = (size_t)b * TSEQ + qwh + g * 4 + r;
    size_t rowl = (size_t)b * TSEQ + qwl + g * 4 + r;
    unsigned short* oph = attn_out + rowh * 1024 + h * 64 + c;
    unsigned short* opl = attn_out + rowl * 1024 + h * 64 + c;
#pragma unroll
    for (int dc = 0; dc < 4; ++dc) {
      oph[dc * 16] = f2bf(oh[dc][r] * invh);
      opl[dc * 16] = f2bf(ol[dc][r] * invl);
    }
  }
#undef LOADT
#undef WRITET
#undef COMPQ
}

extern "C" void kernel_launch(void* const* d_in, const int* in_sizes, int n_in,
                              void* d_out, int out_size, void* d_ws, size_t ws_size,
                              hipStream_t stream) {
  const float* x    = (const float*)d_in[0];
  const float* ln1w = (const float*)d_in[1];
  const float* ln2w = (const float*)d_in[2];
  const float* Wq   = (const float*)d_in[3];
  const float* bq   = (const float*)d_in[4];
  const float* Wk   = (const float*)d_in[5];
  const float* bk   = (const float*)d_in[6];
  const float* Wv   = (const float*)d_in[7];
  const float* bv   = (const float*)d_in[8];
  const float* Wo   = (const float*)d_in[9];
  const float* bo   = (const float*)d_in[10];
  const float* Wup  = (const float*)d_in[11];
  const float* bup  = (const float*)d_in[12];
  const float* Wdn  = (const float*)d_in[13];
  const float* bdn  = (const float*)d_in[14];

  char* ws = (char*)d_ws;
  unsigned short* xn1   = (unsigned short*)(ws + 0);              // 8 MB [4096][1024] bf16
  unsigned short* vtb   = (unsigned short*)(ws + 0);              // 8 MB [32][64][2048] bf16 (aliases xn1, dead by then)
  unsigned short* qkv   = (unsigned short*)(ws + (8ull << 20));   // 24 MB [4096][3072] bf16
  unsigned short* gbuf  = (unsigned short*)(ws + 0);              // 32 MB, aliases vtb+qkv (both dead)
  unsigned short* attn  = (unsigned short*)(ws + (32ull << 20));  // 8 MB [4096][1024] bf16
  float*          x2    = (float*)(ws + (40ull << 20));           // 16 MB [4096][1024] f32
  unsigned short* h2    = (unsigned short*)(ws + (56ull << 20));  // 8 MB
  unsigned short* WqkvT = (unsigned short*)(ws + (64ull << 20));  // 6 MB [3072][1024]
  unsigned short* WoT   = (unsigned short*)(ws + (70ull << 20));  // 2 MB [1024][1024]
  unsigned short* WupT  = (unsigned short*)(ws + (72ull << 20));  // 8 MB [4096][1024]
  unsigned short* WdnT  = (unsigned short*)(ws + (80ull << 20));  // 8 MB [1024][4096]
  float*          bqkv  = (float*)(ws + (88ull << 20));           // 12 KB [3072]

  dim3 blk(256);
  dim3 blk512(512);
  // weight transposes (fp32 -> bf16 W^T)
  tr_kernel<<<dim3(32, 32), blk, 0, stream>>>(Wq, WqkvT, 1024, 1024);
  tr_kernel<<<dim3(32, 32), blk, 0, stream>>>(Wk, WqkvT + 1024 * 1024, 1024, 1024);
  tr_kernel<<<dim3(32, 32), blk, 0, stream>>>(Wv, WqkvT + 2 * 1024 * 1024, 1024, 1024);
  tr_kernel<<<dim3(32, 32), blk, 0, stream>>>(Wo, WoT, 1024, 1024);
  tr_kernel<<<dim3(128, 32), blk, 0, stream>>>(Wup, WupT, 1024, 4096);
  tr_kernel<<<dim3(32, 128), blk, 0, stream>>>(Wdn, WdnT, 4096, 1024);
  concat3_kernel<<<dim3(4), blk, 0, stream>>>(bq, bk, bv, bqkv, 1024);

  // x -> rmsnorm -> qkv (256^2 dbuf tile: grid 12x16 = 192 blocks, %8==0)
  rmsnorm_kernel<<<dim3(NROW), blk, 0, stream>>>(x, ln1w, xn1);
  gemm_db256<0><<<dim3(12, 16), blk512, 0, stream>>>(xn1, WqkvT, bqkv, nullptr, qkv, NROW, 3072, 1024);

  // V transpose then attention (paired causal tiles: 512 uniform blocks)
  vtr_kernel<<<dim3(32, 32), blk, 0, stream>>>(qkv, vtb);
  attn_kernel<<<dim3(512), blk, 0, stream>>>(qkv, vtb, attn);

  // x2 = x + attn @ Wo + bo (narrow N=1024: 128^2 dbuf path)
  gemm_bt<1><<<dim3(8, 32), blk, 0, stream>>>(attn, WoT, bo, x, x2, NROW, 1024, 1024);

  // mlp
  rmsnorm_kernel<<<dim3(NROW), blk, 0, stream>>>(x2, ln2w, h2);
  gemm_db256<2><<<dim3(16, 16), blk512, 0, stream>>>(h2, WupT, bup, nullptr, gbuf, NROW, 4096, 1024);
  gemm_bt<1><<<dim3(8, 32), blk, 0, stream>>>(gbuf, WdnT, bdn, x2, d_out, NROW, 1024, 4096);
}

// Round 12
// 390.388 us; speedup vs baseline: 1.2994x; 1.0682x over previous
//
#include <hip/hip_runtime.h>
#include <cmath>

#define DM   1024
#define HDS  16
#define DH   64
#define DMLP 4096
#define TSEQ 2048
#define NROW 4096   // B*T = 2*2048

typedef short bf16x8 __attribute__((ext_vector_type(8)));
typedef float f32x4 __attribute__((ext_vector_type(4)));

__device__ __forceinline__ unsigned short f2bf(float f) {
  union { float f; unsigned u; } v; v.f = f;
  unsigned r = v.u + 0x7fffu + ((v.u >> 16) & 1u);
  return (unsigned short)(r >> 16);
}

__device__ __forceinline__ void gload_lds16(const void* g, void* l) {
  __builtin_amdgcn_global_load_lds(
      (const __attribute__((address_space(1))) unsigned int*)g,
      (__attribute__((address_space(3))) unsigned int*)l, 16, 0, 0);
}

// ---------- transpose fp32 [K][N] -> bf16 [N][K] ----------
__global__ __launch_bounds__(256) void tr_kernel(const float* __restrict__ in,
                                                 unsigned short* __restrict__ out,
                                                 int K, int N) {
  __shared__ unsigned short tile[32][33];
  int n0 = blockIdx.x * 32, k0 = blockIdx.y * 32;
  int tx = threadIdx.x & 31, ty = threadIdx.x >> 5;
#pragma unroll
  for (int j = 0; j < 4; ++j) {
    int k = ty + j * 8;
    tile[k][tx] = f2bf(in[(size_t)(k0 + k) * N + n0 + tx]);
  }
  __syncthreads();
#pragma unroll
  for (int j = 0; j < 4; ++j) {
    int n = ty + j * 8;
    out[(size_t)(n0 + n) * K + k0 + tx] = tile[tx][n];
  }
}

__global__ void concat3_kernel(const float* __restrict__ a, const float* __restrict__ b,
                               const float* __restrict__ c, float* __restrict__ out, int n) {
  int i = blockIdx.x * 256 + threadIdx.x;
  if (i < n) { out[i] = a[i]; out[n + i] = b[i]; out[2 * n + i] = c[i]; }
}

// ---------- rmsnorm fp32 [NROW][DM] -> bf16 ----------
__global__ __launch_bounds__(256) void rmsnorm_kernel(const float* __restrict__ x,
                                                      const float* __restrict__ w,
                                                      unsigned short* __restrict__ out) {
  int row = blockIdx.x;
  int t = threadIdx.x;
  const float4* xr = (const float4*)(x + (size_t)row * DM);
  float4 v = xr[t];
  float ss = v.x * v.x + v.y * v.y + v.z * v.z + v.w * v.w;
#pragma unroll
  for (int m = 1; m < 64; m <<= 1) ss += __shfl_xor(ss, m, 64);
  __shared__ float sred[4];
  if ((t & 63) == 0) sred[t >> 6] = ss;
  __syncthreads();
  ss = sred[0] + sred[1] + sred[2] + sred[3];
  float norm = rsqrtf(ss * (1.0f / DM) + 1e-6f);
  float4 wv = ((const float4*)w)[t];
  ushort4 o;
  o.x = f2bf(v.x * norm * wv.x);
  o.y = f2bf(v.y * norm * wv.y);
  o.z = f2bf(v.z * norm * wv.z);
  o.w = f2bf(v.w * norm * wv.w);
  ((ushort4*)out)[(size_t)row * (DM / 4) + t] = o;
}

// ---------- split-K reduce: out = p0 + p1 + bias + res (all f32) ----------
__global__ __launch_bounds__(256) void reduce_sk(const float* __restrict__ part,
                                                 const float* __restrict__ bias,
                                                 const float* __restrict__ res,
                                                 float* __restrict__ out, int MN, int N) {
  size_t i = (size_t)blockIdx.x * 256 + threadIdx.x;  // float4 index
  const float4* p0 = (const float4*)part;
  const float4* p1 = p0 + (MN >> 2);
  float4 a = p0[i], b = p1[i], r = ((const float4*)res)[i];
  float4 bi = ((const float4*)bias)[i & ((N >> 2) - 1)];
  float4 o;
  o.x = a.x + b.x + r.x + bi.x;
  o.y = a.y + b.y + r.y + bi.y;
  o.z = a.z + b.z + r.z + bi.z;
  o.w = a.w + b.w + r.w + bi.w;
  ((float4*)out)[i] = o;
}

// ---------- GEMM 128x128 tile, BK=64, dbuf + row&7 slot swizzle ----------
// EPI: 1 = +bias + res -> f32 ; 3 = raw f32 partial (split-K plane blockIdx.z)
// klen = K-extent this block accumulates; kbase = blockIdx.z * klen.
// XCD swizzle on (x,y) grid; grid.x*grid.y must be %8==0.
template <int EPI>
__global__ __launch_bounds__(256) void gemm_bt(const unsigned short* __restrict__ A,
                                               const unsigned short* __restrict__ BT,
                                               const float* __restrict__ bias,
                                               const float* __restrict__ res,
                                               void* __restrict__ outp,
                                               int M, int N, int K, int klen) {
  __shared__ alignas(16) unsigned short As[2][128 * 64];  // 2 x 16 KB
  __shared__ alignas(16) unsigned short Bs[2][128 * 64];  // 2 x 16 KB
  int tid = threadIdx.x;
  int w = tid >> 6, l = tid & 63;
  unsigned nx = gridDim.x;
  unsigned bidl = blockIdx.y * nx + blockIdx.x;
  unsigned nwg = nx * gridDim.y;
  unsigned cpx = nwg >> 3;
  unsigned sb = (bidl & 7) * cpx + (bidl >> 3);
  int m0 = (int)(sb / nx) * 128, n0 = (int)(sb % nx) * 128;
  int wr = w >> 1, wc = w & 1;
  int kbase = (int)blockIdx.z * klen;
  f32x4 acc[4][4];
#pragma unroll
  for (int i = 0; i < 4; ++i)
#pragma unroll
    for (int j = 0; j < 4; ++j)
#pragma unroll
      for (int e = 0; e < 4; ++e) acc[i][j][e] = 0.0f;

  int nk = klen >> 6;
  int srow = tid >> 3;                       // 32 rows per quarter-stage
  int gslot = (tid & 7) ^ (srow & 7);        // pre-swizzled source 16B slot
  int c = l & 15, g = l >> 4;

#define STG128(BUF, KT)                                                            \
  {                                                                                \
    _Pragma("unroll") for (int i = 0; i < 4; ++i) {                                \
      int row = i * 32 + srow;                                                     \
      gload_lds16(A + (size_t)(m0 + row) * K + kbase + (size_t)(KT) * 64 + gslot * 8, \
                  (char*)As[BUF] + i * 4096 + w * 1024);                           \
      gload_lds16(BT + (size_t)(n0 + row) * K + kbase + (size_t)(KT) * 64 + gslot * 8, \
                  (char*)Bs[BUF] + i * 4096 + w * 1024);                           \
    }                                                                              \
  }

  STG128(0, 0);
  __syncthreads();
  int cur = 0;
  for (int kt = 0; kt < nk; ++kt) {
    if (kt + 1 < nk) STG128(cur ^ 1, kt + 1);
#pragma unroll
    for (int ks = 0; ks < 2; ++ks) {
      bf16x8 bfr[4];
#pragma unroll
      for (int nt = 0; nt < 4; ++nt) {
        int brow = wc * 64 + nt * 16 + c;
        unsigned bslot = (unsigned)((ks * 4 + g) ^ (brow & 7));
        bfr[nt] = *(const bf16x8*)((const char*)Bs[cur] + (size_t)brow * 128 + bslot * 16);
      }
#pragma unroll
      for (int mt = 0; mt < 4; ++mt) {
        int arow2 = wr * 64 + mt * 16 + c;
        unsigned aslot2 = (unsigned)((ks * 4 + g) ^ (arow2 & 7));
        bf16x8 af = *(const bf16x8*)((const char*)As[cur] + (size_t)arow2 * 128 + aslot2 * 16);
#pragma unroll
        for (int nt = 0; nt < 4; ++nt)
          acc[mt][nt] = __builtin_amdgcn_mfma_f32_16x16x32_bf16(af, bfr[nt], acc[mt][nt], 0, 0, 0);
      }
    }
    __syncthreads();  // drains vmcnt(0)+lgkmcnt(0) then barrier
    cur ^= 1;
  }
#undef STG128

  float* po = (float*)outp + (size_t)blockIdx.z * M * N;  // z=0 unless split-K
#pragma unroll
  for (int mt = 0; mt < 4; ++mt) {
#pragma unroll
    for (int nt = 0; nt < 4; ++nt) {
#pragma unroll
      for (int r = 0; r < 4; ++r) {
        int m = m0 + wr * 64 + mt * 16 + g * 4 + r;
        int n = n0 + wc * 64 + nt * 16 + c;
        float v = acc[mt][nt][r];
        if (EPI == 1) {
          v += bias[n] + res[(size_t)m * N + n];
          ((float*)outp)[(size_t)m * N + n] = v;
        } else {  // EPI == 3: raw partial
          po[(size_t)m * N + n] = v;
        }
      }
    }
  }
}

// ---------- GEMM 256x256, BK=64, 8 waves, double-buffered + T2 swizzle ----------
// LDS dest linear (global_load_lds requirement); bank swizzle achieved by
// inverse-permuting the GLOBAL source 16B-slot (slot ^= row&7) and applying the
// same XOR on the ds_read side (rule #21: both-sides-or-neither involution).
template <int EPI>
__global__ __launch_bounds__(512) void gemm_db256(const unsigned short* __restrict__ A,
                                                  const unsigned short* __restrict__ BT,
                                                  const float* __restrict__ bias,
                                                  const float* __restrict__ res,
                                                  void* __restrict__ outp,
                                                  int M, int N, int K) {
  __shared__ alignas(16) unsigned short As[2][256 * 64];  // 2 x 32 KB
  __shared__ alignas(16) unsigned short Bs[2][256 * 64];  // 2 x 32 KB
  int tid = threadIdx.x;
  int w = tid >> 6, l = tid & 63;
  int wr = w >> 2, wc = w & 3;  // 2M x 4N waves
  unsigned nx = gridDim.x;
  unsigned bidl = blockIdx.y * nx + blockIdx.x;
  unsigned nwg = nx * gridDim.y;
  unsigned cpx = nwg >> 3;  // grid must be %8==0
  unsigned sb = (bidl & 7) * cpx + (bidl >> 3);
  int m0 = (int)(sb / nx) * 256, n0 = (int)(sb % nx) * 256;

  f32x4 acc[8][4];
#pragma unroll
  for (int i = 0; i < 8; ++i)
#pragma unroll
    for (int j = 0; j < 4; ++j)
#pragma unroll
      for (int e = 0; e < 4; ++e) acc[i][j][e] = 0.0f;

  int nk = K >> 6;
  int srow = tid >> 3, sslot = tid & 7;  // 64 rows x 8 slots per stage inst
  int gslot = sslot ^ (srow & 7);        // pre-swizzled source slot
  int c = l & 15, g = l >> 4;

#define STG256(BUF, KT)                                                            \
  {                                                                                \
    _Pragma("unroll") for (int i = 0; i < 4; ++i) {                                \
      int row = i * 64 + srow;                                                     \
      gload_lds16(A + (size_t)(m0 + row) * K + (size_t)(KT) * 64 + gslot * 8,      \
                  (char*)As[BUF] + i * 8192 + w * 1024);                           \
      gload_lds16(BT + (size_t)(n0 + row) * K + (size_t)(KT) * 64 + gslot * 8,     \
                  (char*)Bs[BUF] + i * 8192 + w * 1024);                           \
    }                                                                              \
  }

  STG256(0, 0);
  __syncthreads();
  int cur = 0;
  for (int kt = 0; kt < nk; ++kt) {
    if (kt + 1 < nk) STG256(cur ^ 1, kt + 1);
#pragma unroll
    for (int ks = 0; ks < 2; ++ks) {
      bf16x8 bfr[4];
#pragma unroll
      for (int nt = 0; nt < 4; ++nt) {
        int brow = wc * 64 + nt * 16 + c;
        unsigned bslot = (unsigned)((ks * 4 + g) ^ (brow & 7));
        bfr[nt] = *(const bf16x8*)((const char*)Bs[cur] + (size_t)brow * 128 + bslot * 16);
      }
#pragma unroll
      for (int mt = 0; mt < 8; ++mt) {
        int arow2 = wr * 128 + mt * 16 + c;
        unsigned aslot2 = (unsigned)((ks * 4 + g) ^ (arow2 & 7));
        bf16x8 af = *(const bf16x8*)((const char*)As[cur] + (size_t)arow2 * 128 + aslot2 * 16);
#pragma unroll
        for (int nt = 0; nt < 4; ++nt)
          acc[mt][nt] = __builtin_amdgcn_mfma_f32_16x16x32_bf16(af, bfr[nt], acc[mt][nt], 0, 0, 0);
      }
    }
    __syncthreads();  // drains vmcnt(0)+lgkmcnt(0) then barrier
    cur ^= 1;
  }
#undef STG256

#pragma unroll
  for (int mt = 0; mt < 8; ++mt) {
#pragma unroll
    for (int nt = 0; nt < 4; ++nt) {
#pragma unroll
      for (int r = 0; r < 4; ++r) {
        int m = m0 + wr * 128 + mt * 16 + g * 4 + r;
        int n = n0 + wc * 64 + nt * 16 + c;
        float v = acc[mt][nt][r] + bias[n];
        if (EPI == 2) v = 0.5f * v * (1.0f + erff(v * 0.70710678118654752f));
        if (EPI == 1) {
          v += res[(size_t)m * N + n];
          ((float*)outp)[(size_t)m * N + n] = v;
        } else {
          ((unsigned short*)outp)[(size_t)m * N + n] = f2bf(v);
        }
      }
    }
  }
}

// ---------- V transpose: qkv v-part -> VT [bh][64 d][2048 t] bf16 ----------
__global__ __launch_bounds__(256) void vtr_kernel(const unsigned short* __restrict__ qkv,
                                                  unsigned short* __restrict__ vt) {
  __shared__ unsigned short tile[64][72];
  int bh = blockIdx.y, t0 = blockIdx.x * 64;
  int b = bh >> 4, h = bh & 15;
  int r = threadIdx.x >> 3, sl = threadIdx.x & 7;
#pragma unroll
  for (int half = 0; half < 2; ++half) {
    int rr = r + half * 32;
    bf16x8 v = *(const bf16x8*)(qkv + (size_t)(b * TSEQ + t0 + rr) * 3072 + 2048 + h * 64 + sl * 8);
    *(bf16x8*)&tile[rr][sl * 8] = v;  // row stride 144B (16B-aligned)
  }
  __syncthreads();
#pragma unroll
  for (int half = 0; half < 2; ++half) {
    int d = r + half * 32;
    bf16x8 o;
#pragma unroll
    for (int j = 0; j < 8; ++j) o[j] = (short)tile[sl * 8 + j][d];
    *(bf16x8*)(vt + ((size_t)bh * 64 + d) * TSEQ + t0 + sl * 8) = o;
  }
}

// ---------- causal flash attention v5: paired q-tiles for load balance ----------
// Block handles q-tiles (qb_lo=pair, qb_hi=31-pair) of one (b,h): compute-tiles
// per wave = (32-pair)+(pair+1) = 33, uniform across all 512 blocks. Both
// q-tiles share each staged K/V tile. 4 waves x 16 q-rows per q-tile; KVBLK=64;
// swizzled LDS; full online-softmax; deferred final l-reduce.
__global__ __launch_bounds__(256) void attn_kernel(const unsigned short* __restrict__ qkv,
                                                   const unsigned short* __restrict__ vt,
                                                   unsigned short* __restrict__ attn_out) {
  __shared__ alignas(16) unsigned short Ks[2][64 * 64];     // [k][d] swz
  __shared__ alignas(16) unsigned short Vs[2][64 * 64];     // [d][k] swz
  __shared__ alignas(16) unsigned short Ps[4][2][16 * 64];  // per-wave, per-qtile
  int tid = threadIdx.x, w = tid >> 6, l = tid & 63, g = l >> 4, c = l & 15;
  int bid = blockIdx.x;
  int pair = bid & 15;
  int bh = bid >> 4, b = bh >> 4, h = bh & 15;
  int qbh = 31 - pair, qbl = pair;
  int qwh = qbh * 64 + w * 16;
  int qwl = qbl * 64 + w * 16;

  // Q fragments for both q-tiles: rows qw + c, d-slices s*32 + g*8
  bf16x8 qfh[2], qfl[2];
#pragma unroll
  for (int s = 0; s < 2; ++s) {
    qfh[s] = *(const bf16x8*)(qkv + (size_t)(b * TSEQ + qwh + c) * 3072 + h * 64 + s * 32 + g * 8);
    qfl[s] = *(const bf16x8*)(qkv + (size_t)(b * TSEQ + qwl + c) * 3072 + h * 64 + s * 32 + g * 8);
  }

  f32x4 oh[4], ol[4];
  float mh[4], lh[4], ml[4], ll[4];
#pragma unroll
  for (int dc = 0; dc < 4; ++dc)
#pragma unroll
    for (int e = 0; e < 4; ++e) { oh[dc][e] = 0.0f; ol[dc][e] = 0.0f; }
#pragma unroll
  for (int r = 0; r < 4; ++r) { mh[r] = -1e30f; lh[r] = 0.0f; ml[r] = -1e30f; ll[r] = 0.0f; }

  int ntile = qbh + 1;
  int sr = tid >> 3, ss = tid & 7;  // staging: 32 rows x 8 slots, 2 halves
  bf16x8 kreg[2], vreg[2];

#define LOADT(K0)                                                                       \
  {                                                                                     \
    _Pragma("unroll") for (int hf = 0; hf < 2; ++hf) {                                  \
      int rr = sr + hf * 32;                                                            \
      kreg[hf] = *(const bf16x8*)(qkv + (size_t)(b * TSEQ + (K0) + rr) * 3072 + 1024 +  \
                                  h * 64 + ss * 8);                                     \
      vreg[hf] = *(const bf16x8*)(vt + ((size_t)bh * 64 + rr) * TSEQ + (K0) + ss * 8);  \
    }                                                                                   \
  }
#define WRITET(BUF)                                                                     \
  {                                                                                     \
    _Pragma("unroll") for (int hf = 0; hf < 2; ++hf) {                                  \
      int rr = sr + hf * 32;                                                            \
      unsigned off = (unsigned)(rr * 128 + ss * 16) ^ (unsigned)((rr & 7) << 4);        \
      *(bf16x8*)((char*)Ks[BUF] + off) = kreg[hf];                                      \
      *(bf16x8*)((char*)Vs[BUF] + off) = vreg[hf];                                      \
    }                                                                                   \
  }
// one q-tile's QK -> softmax -> P -> PV against the staged tile
#define COMPQ(QF, O, MR, LP, QW, PSL)                                                   \
  {                                                                                     \
    f32x4 s_[4];                                                                        \
    _Pragma("unroll") for (int ni = 0; ni < 4; ++ni) {                                  \
      int krow_ = ni * 16 + c;                                                          \
      unsigned swz_ = (unsigned)((c & 7) << 4);                                         \
      bf16x8 kf0_ = *(const bf16x8*)(Kb + (((unsigned)(krow_ * 128) + g * 16) ^ swz_)); \
      bf16x8 kf1_ = *(const bf16x8*)(Kb + (((unsigned)(krow_ * 128) + 64 + g * 16) ^ swz_)); \
      f32x4 a_;                                                                         \
      _Pragma("unroll") for (int e = 0; e < 4; ++e) a_[e] = 0.0f;                       \
      a_ = __builtin_amdgcn_mfma_f32_16x16x32_bf16(QF[0], kf0_, a_, 0, 0, 0);           \
      a_ = __builtin_amdgcn_mfma_f32_16x16x32_bf16(QF[1], kf1_, a_, 0, 0, 0);           \
      s_[ni] = a_;                                                                      \
    }                                                                                   \
    bool full_ = (k0 + 63 <= (QW));                                                     \
    _Pragma("unroll") for (int r = 0; r < 4; ++r) {                                     \
      int qg_ = (QW) + g * 4 + r;                                                       \
      float pm_[4];                                                                     \
      _Pragma("unroll") for (int ni = 0; ni < 4; ++ni) {                                \
        float v_ = s_[ni][r] * 0.125f;                                                  \
        if (!full_) {                                                                   \
          int kg_ = k0 + ni * 16 + c;                                                   \
          v_ = (kg_ <= qg_) ? v_ : -1e30f;                                              \
        }                                                                               \
        pm_[ni] = v_;                                                                   \
      }                                                                                 \
      float mx_ = fmaxf(fmaxf(pm_[0], pm_[1]), fmaxf(pm_[2], pm_[3]));                  \
      mx_ = fmaxf(mx_, __shfl_xor(mx_, 1, 64));                                         \
      mx_ = fmaxf(mx_, __shfl_xor(mx_, 2, 64));                                         \
      mx_ = fmaxf(mx_, __shfl_xor(mx_, 4, 64));                                         \
      mx_ = fmaxf(mx_, __shfl_xor(mx_, 8, 64));                                         \
      float mnew_ = fmaxf(MR[r], mx_);                                                  \
      float scale_ = __expf(MR[r] - mnew_);                                             \
      MR[r] = mnew_;                                                                    \
      float p_[4], rs_ = 0.0f;                                                          \
      _Pragma("unroll") for (int ni = 0; ni < 4; ++ni) {                                \
        p_[ni] = __expf(pm_[ni] - mnew_); rs_ += p_[ni];                                \
      }                                                                                 \
      LP[r] = LP[r] * scale_ + rs_;                                                     \
      _Pragma("unroll") for (int dc = 0; dc < 4; ++dc) O[dc][r] *= scale_;              \
      int prow_ = g * 4 + r;                                                            \
      unsigned pswz_ = (unsigned)((prow_ & 7) << 4);                                    \
      _Pragma("unroll") for (int ni = 0; ni < 4; ++ni)                                  \
        *(unsigned short*)((char*)Ps[w][PSL] +                                          \
            (((unsigned)(prow_ * 128 + (ni * 16 + c) * 2)) ^ pswz_)) = f2bf(p_[ni]);    \
    }                                                                                   \
    asm volatile("s_waitcnt lgkmcnt(0)" ::: "memory");                                  \
    unsigned swz2_ = (unsigned)((c & 7) << 4);                                          \
    _Pragma("unroll") for (int kc = 0; kc < 2; ++kc) {                                  \
      bf16x8 pf_ = *(const bf16x8*)((const char*)Ps[w][PSL] +                           \
                    (((unsigned)(c * 128 + kc * 64 + g * 16)) ^ swz2_));                \
      _Pragma("unroll") for (int dc = 0; dc < 4; ++dc) {                                \
        bf16x8 vf_ = *(const bf16x8*)(Vb +                                              \
                      (((unsigned)((dc * 16 + c) * 128 + kc * 64 + g * 16)) ^ swz2_));  \
        O[dc] = __builtin_amdgcn_mfma_f32_16x16x32_bf16(pf_, vf_, O[dc], 0, 0, 0);      \
      }                                                                                 \
    }                                                                                   \
  }

  LOADT(0);
  WRITET(0);
  __syncthreads();

  for (int t = 0; t < ntile; ++t) {
    int k0 = t << 6, cur = t & 1;
    if (t + 1 < ntile) LOADT((t + 1) << 6);

    {
      const char* Kb = (const char*)Ks[cur];
      const char* Vb = (const char*)Vs[cur];
      // hi q-tile: needed for every staged tile
      COMPQ(qfh, oh, mh, lh, qwh, 0);
      // lo q-tile: only first (pair+1) tiles
      if (k0 <= qwl + 15) COMPQ(qfl, ol, ml, ll, qwl, 1);
    }

    if (t + 1 < ntile) {
      WRITET(cur ^ 1);
      __syncthreads();
    }
  }

#pragma unroll
  for (int r = 0; r < 4; ++r) {
    float lrh = lh[r], lrl = ll[r];
    lrh += __shfl_xor(lrh, 1, 64);
    lrh += __shfl_xor(lrh, 2, 64);
    lrh += __shfl_xor(lrh, 4, 64);
    lrh += __shfl_xor(lrh, 8, 64);
    lrl += __shfl_xor(lrl, 1, 64);
    lrl += __shfl_xor(lrl, 2, 64);
    lrl += __shfl_xor(lrl, 4, 64);
    lrl += __shfl_xor(lrl, 8, 64);
    float invh = 1.0f / lrh, invl = 1.0f / lrl;
    size_t rowh = (size_t)b * TSEQ + qwh + g * 4 + r;
    size_t rowl = (size_t)b * TSEQ + qwl + g * 4 + r;
    unsigned short* oph = attn_out + rowh * 1024 + h * 64 + c;
    unsigned short* opl = attn_out + rowl * 1024 + h * 64 + c;
#pragma unroll
    for (int dc = 0; dc < 4; ++dc) {
      oph[dc * 16] = f2bf(oh[dc][r] * invh);
      opl[dc * 16] = f2bf(ol[dc][r] * invl);
    }
  }
#undef LOADT
#undef WRITET
#undef COMPQ
}

extern "C" void kernel_launch(void* const* d_in, const int* in_sizes, int n_in,
                              void* d_out, int out_size, void* d_ws, size_t ws_size,
                              hipStream_t stream) {
  const float* x    = (const float*)d_in[0];
  const float* ln1w = (const float*)d_in[1];
  const float* ln2w = (const float*)d_in[2];
  const float* Wq   = (const float*)d_in[3];
  const float* bq   = (const float*)d_in[4];
  const float* Wk   = (const float*)d_in[5];
  const float* bk   = (const float*)d_in[6];
  const float* Wv   = (const float*)d_in[7];
  const float* bv   = (const float*)d_in[8];
  const float* Wo   = (const float*)d_in[9];
  const float* bo   = (const float*)d_in[10];
  const float* Wup  = (const float*)d_in[11];
  const float* bup  = (const float*)d_in[12];
  const float* Wdn  = (const float*)d_in[13];
  const float* bdn  = (const float*)d_in[14];

  char* ws = (char*)d_ws;
  unsigned short* xn1   = (unsigned short*)(ws + 0);              // 8 MB [4096][1024] bf16
  unsigned short* vtb   = (unsigned short*)(ws + 0);              // 8 MB (aliases xn1, dead by then)
  unsigned short* qkv   = (unsigned short*)(ws + (8ull << 20));   // 24 MB [4096][3072] bf16
  unsigned short* gbuf  = (unsigned short*)(ws + 0);              // 32 MB, aliases vtb+qkv (both dead)
  unsigned short* attn  = (unsigned short*)(ws + (32ull << 20));  // 8 MB [4096][1024] bf16
  float*          x2    = (float*)(ws + (40ull << 20));           // 16 MB [4096][1024] f32
  unsigned short* h2    = (unsigned short*)(ws + (56ull << 20));  // 8 MB
  unsigned short* WqkvT = (unsigned short*)(ws + (64ull << 20));  // 6 MB [3072][1024]
  unsigned short* WoT   = (unsigned short*)(ws + (70ull << 20));  // 2 MB [1024][1024]
  unsigned short* WupT  = (unsigned short*)(ws + (72ull << 20));  // 8 MB [4096][1024]
  unsigned short* WdnT  = (unsigned short*)(ws + (80ull << 20));  // 8 MB [1024][4096]
  float*          bqkv  = (float*)(ws + (88ull << 20));           // 12 KB [3072]
  float*          part  = (float*)(ws + (96ull << 20));           // 32 MB split-K partials

  bool sk = ws_size >= (128ull << 20);

  dim3 blk(256);
  dim3 blk512(512);
  // weight transposes (fp32 -> bf16 W^T)
  tr_kernel<<<dim3(32, 32), blk, 0, stream>>>(Wq, WqkvT, 1024, 1024);
  tr_kernel<<<dim3(32, 32), blk, 0, stream>>>(Wk, WqkvT + 1024 * 1024, 1024, 1024);
  tr_kernel<<<dim3(32, 32), blk, 0, stream>>>(Wv, WqkvT + 2 * 1024 * 1024, 1024, 1024);
  tr_kernel<<<dim3(32, 32), blk, 0, stream>>>(Wo, WoT, 1024, 1024);
  tr_kernel<<<dim3(128, 32), blk, 0, stream>>>(Wup, WupT, 1024, 4096);
  tr_kernel<<<dim3(32, 128), blk, 0, stream>>>(Wdn, WdnT, 4096, 1024);
  concat3_kernel<<<dim3(4), blk, 0, stream>>>(bq, bk, bv, bqkv, 1024);

  // x -> rmsnorm -> qkv (256^2 dbuf tile: grid 12x16 = 192 blocks, %8==0)
  rmsnorm_kernel<<<dim3(NROW), blk, 0, stream>>>(x, ln1w, xn1);
  gemm_db256<0><<<dim3(12, 16), blk512, 0, stream>>>(xn1, WqkvT, bqkv, nullptr, qkv, NROW, 3072, 1024);

  // V transpose then attention (paired causal tiles: 512 uniform blocks)
  vtr_kernel<<<dim3(32, 32), blk, 0, stream>>>(qkv, vtb);
  attn_kernel<<<dim3(512), blk, 0, stream>>>(qkv, vtb, attn);

  // x2 = x + attn @ Wo + bo (128^2 BK=64 dbuf path)
  gemm_bt<1><<<dim3(8, 32), blk, 0, stream>>>(attn, WoT, bo, x, x2, NROW, 1024, 1024, 1024);

  // mlp
  rmsnorm_kernel<<<dim3(NROW), blk, 0, stream>>>(x2, ln2w, h2);
  gemm_db256<2><<<dim3(16, 16), blk512, 0, stream>>>(h2, WupT, bup, nullptr, gbuf, NROW, 4096, 1024);
  if (sk) {
    // split-K=2: 512 concurrent blocks (2/CU), partials -> reduce
    gemm_bt<3><<<dim3(8, 32, 2), blk, 0, stream>>>(gbuf, WdnT, nullptr, nullptr, part,
                                                   NROW, 1024, 4096, 2048);
    reduce_sk<<<dim3(4096), blk, 0, stream>>>(part, bdn, x2, (float*)d_out, NROW * 1024, 1024);
  } else {
    gemm_bt<1><<<dim3(8, 32), blk, 0, stream>>>(gbuf, WdnT, bdn, x2, d_out, NROW, 1024, 4096, 4096);
  }
}